// Round 1
// baseline (1445.104 us; speedup 1.0000x reference)
//
#include <hip/hip_runtime.h>
#include <cstddef>
#include <cstdint>

// ---------------------------------------------------------------------------
// MetaSR fused pipeline, fp32 baseline.
//   K1: conv encoder -> feat padded [16][34][34][34] (borders zero)
//   K2: U[vox][256]  = W5 . feat_u(:,vox)   (hoists layer-5 out of the query loop)
//       s[vox]       = b5 . feat_u(:,vox)
//   K3: per 32-query block: x -> L1(4x256) -> L2,L3,L4 (256x256, LDS ping-pong)
//       -> out[q] = h4 . U[vox] + s[vox]
// ---------------------------------------------------------------------------

#define FPC (34*34*34)   // 39304  per-channel stride of padded feat
#define FPD (34*34)      // 1156

// ---------------- K1: conv encoder ----------------
__global__ void conv_enc_kernel(const float* __restrict__ inp,
                                const float* __restrict__ Wenc,
                                const float* __restrict__ benc,
                                float* __restrict__ featp)
{
    __shared__ float wl[432];
    __shared__ float bl[16];
    int t = threadIdx.x;
    for (int k = t; k < 432; k += 256) wl[k] = Wenc[k];
    if (t < 16) bl[t] = benc[t];
    __syncthreads();

    int vid = blockIdx.x * 256 + t;            // 0..32767
    int d = vid >> 10, h = (vid >> 5) & 31, w = vid & 31;

    float v[27];
    #pragma unroll
    for (int dz = 0; dz < 3; dz++)
      #pragma unroll
      for (int dy = 0; dy < 3; dy++)
        #pragma unroll
        for (int dx = 0; dx < 3; dx++) {
            int zz = d + dz - 1, yy = h + dy - 1, xx = w + dx - 1;
            bool ok = (zz >= 0 && zz < 32 && yy >= 0 && yy < 32 && xx >= 0 && xx < 32);
            v[dz*9 + dy*3 + dx] = ok ? inp[(zz << 10) + (yy << 5) + xx] : 0.0f;
        }

    #pragma unroll
    for (int oc = 0; oc < 16; oc++) {
        float a = bl[oc];
        #pragma unroll
        for (int n = 0; n < 27; n++) a = fmaf(v[n], wl[oc*27 + n], a);
        featp[oc*FPC + (d+1)*FPD + (h+1)*34 + (w+1)] = a;
    }
}

// ---------------- K2: U / s precompute ----------------
// block = 256 threads, 32 voxels per block (same d,h; w = 0..31)
__global__ void u_precompute_kernel(const float* __restrict__ featp,
                                    const float* __restrict__ W5,   // [256][432]
                                    const float* __restrict__ b5,   // [432]
                                    float* __restrict__ U,          // [32768][256]
                                    float* __restrict__ S)          // [32768]
{
    __shared__ float fu[432*32];   // feat_u column for 32 voxels, [k][vv]
    int t = threadIdx.x;
    int d = blockIdx.x >> 5, h = blockIdx.x & 31;

    int kk0 = t >> 5;              // 0..7
    int vv  = t & 31;
    for (int kb = 0; kb < 54; kb++) {
        int k = kb*8 + kk0;
        int c = k / 27, n = k % 27;
        int i = n / 9, j = (n / 3) % 3, x = n % 3;
        fu[k*32 + vv] = featp[c*FPC + (d + i)*FPD + (h + j)*34 + (vv + x)];
    }
    __syncthreads();

    int jt = t & 63, vt = t >> 6;
    int j0 = jt * 4, v0 = vt * 8;
    float acc[8][4];
    #pragma unroll
    for (int a = 0; a < 8; a++)
        #pragma unroll
        for (int b = 0; b < 4; b++) acc[a][b] = 0.0f;

    for (int k = 0; k < 432; k += 4) {
        float4 w0 = *(const float4*)(W5 + (size_t)(j0 + 0)*432 + k);
        float4 w1 = *(const float4*)(W5 + (size_t)(j0 + 1)*432 + k);
        float4 w2 = *(const float4*)(W5 + (size_t)(j0 + 2)*432 + k);
        float4 w3 = *(const float4*)(W5 + (size_t)(j0 + 3)*432 + k);
        float wr[4][4] = {{w0.x,w0.y,w0.z,w0.w},{w1.x,w1.y,w1.z,w1.w},
                          {w2.x,w2.y,w2.z,w2.w},{w3.x,w3.y,w3.z,w3.w}};
        #pragma unroll
        for (int u = 0; u < 4; u++) {
            float4 a0 = *(const float4*)(fu + (k + u)*32 + v0);
            float4 a1 = *(const float4*)(fu + (k + u)*32 + v0 + 4);
            float av[8] = {a0.x,a0.y,a0.z,a0.w,a1.x,a1.y,a1.z,a1.w};
            #pragma unroll
            for (int v = 0; v < 8; v++) {
                acc[v][0] = fmaf(av[v], wr[0][u], acc[v][0]);
                acc[v][1] = fmaf(av[v], wr[1][u], acc[v][1]);
                acc[v][2] = fmaf(av[v], wr[2][u], acc[v][2]);
                acc[v][3] = fmaf(av[v], wr[3][u], acc[v][3]);
            }
        }
    }

    size_t voxbase = (size_t)blockIdx.x * 32;
    #pragma unroll
    for (int v = 0; v < 8; v++) {
        *(float4*)(U + (voxbase + v0 + v)*256 + j0) =
            make_float4(acc[v][0], acc[v][1], acc[v][2], acc[v][3]);
    }

    if (t < 32) {
        float s = 0.0f;
        for (int k = 0; k < 432; k++) s = fmaf(b5[k], fu[k*32 + t], s);
        S[voxbase + t] = s;
    }
}

// ---------------- K3: fused query MLP ----------------
__device__ __forceinline__ void mlp256(const float* __restrict__ Wl,  // [256][256]
                                       const float* __restrict__ bl,
                                       const float* __restrict__ src, // LDS [256][32]
                                       float* __restrict__ dst,       // LDS [256][32]
                                       int j0, int q0)
{
    float acc[8][4];
    float4 bv = *(const float4*)(bl + j0);
    #pragma unroll
    for (int q = 0; q < 8; q++) { acc[q][0]=bv.x; acc[q][1]=bv.y; acc[q][2]=bv.z; acc[q][3]=bv.w; }

    #pragma unroll 4
    for (int i = 0; i < 256; i++) {
        float4 w  = *(const float4*)(Wl + (size_t)i*256 + j0);
        float4 a0 = *(const float4*)(src + i*32 + q0);
        float4 a1 = *(const float4*)(src + i*32 + q0 + 4);
        float av[8] = {a0.x,a0.y,a0.z,a0.w,a1.x,a1.y,a1.z,a1.w};
        #pragma unroll
        for (int q = 0; q < 8; q++) {
            acc[q][0] = fmaf(av[q], w.x, acc[q][0]);
            acc[q][1] = fmaf(av[q], w.y, acc[q][1]);
            acc[q][2] = fmaf(av[q], w.z, acc[q][2]);
            acc[q][3] = fmaf(av[q], w.w, acc[q][3]);
        }
    }
    #pragma unroll
    for (int jj = 0; jj < 4; jj++) {
        *(float4*)(dst + (j0 + jj)*32 + q0) =
            make_float4(fmaxf(acc[0][jj],0.f), fmaxf(acc[1][jj],0.f),
                        fmaxf(acc[2][jj],0.f), fmaxf(acc[3][jj],0.f));
        *(float4*)(dst + (j0 + jj)*32 + q0 + 4) =
            make_float4(fmaxf(acc[4][jj],0.f), fmaxf(acc[5][jj],0.f),
                        fmaxf(acc[6][jj],0.f), fmaxf(acc[7][jj],0.f));
    }
}

__global__ __launch_bounds__(256, 2)
void query_kernel(const float* __restrict__ coord,
                  const float* __restrict__ cell,
                  const float* __restrict__ W1, const float* __restrict__ b1,
                  const float* __restrict__ W2, const float* __restrict__ b2,
                  const float* __restrict__ W3, const float* __restrict__ b3,
                  const float* __restrict__ W4, const float* __restrict__ b4,
                  const float* __restrict__ U,  const float* __restrict__ S,
                  float* __restrict__ out)
{
    __shared__ float hA[8192];   // [neuron][query]
    __shared__ float hB[8192];
    float* xS = hB;              // alias: x[4][32]; dead before L2 writes hB

    int t = threadIdx.x;
    int qbase = blockIdx.x * 32;

    if (t < 32) {
        int gq = qbase + t;
        float c0 = coord[3*gq+0], c1 = coord[3*gq+1], c2 = coord[3*gq+2];
        float e0 = cell[3*gq+0],  e1 = cell[3*gq+1],  e2 = cell[3*gq+2];
        float x0 = c0 - e0*0.5f, x1 = c1 - e1*0.5f, x2 = c2 - e2*0.5f;

        // q_coord: round on UNclipped coord_, all-or-nothing valid mask
        float f0 = rintf(((x0 + 1.0f)*32.0f - 1.0f)*0.5f);
        float f1 = rintf(((x1 + 1.0f)*32.0f - 1.0f)*0.5f);
        float f2 = rintf(((x2 + 1.0f)*32.0f - 1.0f)*0.5f);
        bool valid = (f0 >= 0.0f && f0 < 32.0f &&
                      f1 >= 0.0f && f1 < 32.0f &&
                      f2 >= 0.0f && f2 < 32.0f);
        int i0 = min(max((int)f0, 0), 31);
        int i1 = min(max((int)f1, 0), 31);
        int i2 = min(max((int)f2, 0), 31);
        float qc0 = -0.96875f + 0.0625f*(float)i0;   // (2i+1)/32 - 1, exact dyadic
        float qc1 = -0.96875f + 0.0625f*(float)i1;
        float qc2 = -0.96875f + 0.0625f*(float)i2;
        // ref quirk: fc[:,:,w,:] for w in {0,1,3} gets -1/32 on ALL components
        float adj = (i2 == 0 || i2 == 1 || i2 == 3) ? -0.03125f : 0.0f;
        qc0 += adj; qc1 += adj; qc2 += adj;
        if (!valid) { qc0 = 0.0f; qc1 = 0.0f; qc2 = 0.0f; }

        xS[0*32 + t] = (x0 - qc0)*32.0f;
        xS[1*32 + t] = (x1 - qc1)*32.0f;
        xS[2*32 + t] = (x2 - qc2)*32.0f;
        xS[3*32 + t] = e0 * 16.0f;           // r_rev = cell0 * (H/2)
    }
    __syncthreads();

    int tj = t & 63, tq = t >> 6;
    int j0 = tj*4, q0 = tq*8;

    // ----- layer 1: 4 -> 256 (reads xS in hB, writes hA) -----
    {
        float acc[8][4];
        float4 bv = *(const float4*)(b1 + j0);
        #pragma unroll
        for (int q = 0; q < 8; q++) { acc[q][0]=bv.x; acc[q][1]=bv.y; acc[q][2]=bv.z; acc[q][3]=bv.w; }
        #pragma unroll
        for (int i = 0; i < 4; i++) {
            float4 w = *(const float4*)(W1 + i*256 + j0);
            float av[8];
            #pragma unroll
            for (int q = 0; q < 8; q++) av[q] = xS[i*32 + q0 + q];
            #pragma unroll
            for (int q = 0; q < 8; q++) {
                acc[q][0] = fmaf(av[q], w.x, acc[q][0]);
                acc[q][1] = fmaf(av[q], w.y, acc[q][1]);
                acc[q][2] = fmaf(av[q], w.z, acc[q][2]);
                acc[q][3] = fmaf(av[q], w.w, acc[q][3]);
            }
        }
        #pragma unroll
        for (int jj = 0; jj < 4; jj++) {
            *(float4*)(hA + (j0 + jj)*32 + q0) =
                make_float4(fmaxf(acc[0][jj],0.f), fmaxf(acc[1][jj],0.f),
                            fmaxf(acc[2][jj],0.f), fmaxf(acc[3][jj],0.f));
            *(float4*)(hA + (j0 + jj)*32 + q0 + 4) =
                make_float4(fmaxf(acc[4][jj],0.f), fmaxf(acc[5][jj],0.f),
                            fmaxf(acc[6][jj],0.f), fmaxf(acc[7][jj],0.f));
        }
    }
    __syncthreads();

    mlp256(W2, b2, hA, hB, j0, q0); __syncthreads();
    mlp256(W3, b3, hB, hA, j0, q0); __syncthreads();
    mlp256(W4, b4, hA, hB, j0, q0); __syncthreads();   // h4 now in hB

    // ----- final: out[q] = h4 . U[vox] + s[vox] -----
    int q = t >> 3, part = t & 7;
    int gq = qbase + q;
    // recompute vox from coords (kept out of LDS; hA/hB were both recycled)
    float c0 = coord[3*gq+0], c1 = coord[3*gq+1], c2 = coord[3*gq+2];
    float e0 = cell[3*gq+0],  e1 = cell[3*gq+1],  e2 = cell[3*gq+2];
    const float LO = (float)(-1.0 + 1e-6);
    const float HI = (float)( 1.0 - 1e-6);
    float x0 = fminf(fmaxf(c0 - e0*0.5f + 1e-6f, LO), HI);
    float x1 = fminf(fmaxf(c1 - e1*0.5f + 1e-6f, LO), HI);
    float x2 = fminf(fmaxf(c2 - e2*0.5f + 1e-6f, LO), HI);
    int i0 = min(max((int)rintf(((x0 + 1.0f)*32.0f - 1.0f)*0.5f), 0), 31);
    int i1 = min(max((int)rintf(((x1 + 1.0f)*32.0f - 1.0f)*0.5f), 0), 31);
    int i2 = min(max((int)rintf(((x2 + 1.0f)*32.0f - 1.0f)*0.5f), 0), 31);
    int vox = (i0 << 10) + (i1 << 5) + i2;

    const float* Ur = U + (size_t)vox*256 + part*32;
    float sum = 0.0f;
    #pragma unroll
    for (int jj = 0; jj < 32; jj += 4) {
        float4 u = *(const float4*)(Ur + jj);
        int j = part*32 + jj;
        sum = fmaf(u.x, hB[(j+0)*32 + q], sum);
        sum = fmaf(u.y, hB[(j+1)*32 + q], sum);
        sum = fmaf(u.z, hB[(j+2)*32 + q], sum);
        sum = fmaf(u.w, hB[(j+3)*32 + q], sum);
    }
    sum += __shfl_down(sum, 4);
    sum += __shfl_down(sum, 2);
    sum += __shfl_down(sum, 1);
    if (part == 0) out[gq] = sum + S[vox];
}

// ---------------------------------------------------------------------------
extern "C" void kernel_launch(void* const* d_in, const int* in_sizes, int n_in,
                              void* d_out, int out_size, void* d_ws, size_t ws_size,
                              hipStream_t stream)
{
    const float* inp   = (const float*)d_in[0];
    const float* coord = (const float*)d_in[1];
    const float* cell  = (const float*)d_in[2];
    const float* Wenc  = (const float*)d_in[3];
    const float* benc  = (const float*)d_in[4];
    const float* W1 = (const float*)d_in[5];  const float* b1 = (const float*)d_in[6];
    const float* W2 = (const float*)d_in[7];  const float* b2 = (const float*)d_in[8];
    const float* W3 = (const float*)d_in[9];  const float* b3 = (const float*)d_in[10];
    const float* W4 = (const float*)d_in[11]; const float* b4 = (const float*)d_in[12];
    const float* W5 = (const float*)d_in[13]; const float* b5 = (const float*)d_in[14];
    float* out = (float*)d_out;

    char* ws = (char*)d_ws;
    float* featp = (float*)ws;                              // 16*39304 f = 2,515,456 B
    float* U     = (float*)(ws + 2515456);                  // 32768*256 f = 33,554,432 B
    float* S     = (float*)(ws + 2515456 + 33554432);       // 32768 f

    hipMemsetAsync(featp, 0, (size_t)16*FPC*sizeof(float), stream);
    conv_enc_kernel<<<128, 256, 0, stream>>>(inp, Wenc, benc, featp);
    u_precompute_kernel<<<1024, 256, 0, stream>>>(featp, W5, b5, U, S);
    query_kernel<<<6250, 256, 0, stream>>>(coord, cell, W1,b1, W2,b2, W3,b3, W4,b4,
                                           U, S, out);
}

// Round 4
// 1077.145 us; speedup vs baseline: 1.3416x; 1.3416x over previous
//
#include <hip/hip_runtime.h>
#include <cstddef>
#include <cstdint>

// ---------------------------------------------------------------------------
// MetaSR fused pipeline, MFMA bf16-split version.
//   K1: conv encoder -> feat padded [16][34][34][34] (borders zero)
//   Kp: transpose+split W2/W3/W4 -> Wt[m][k] bf16 hi/lo (once per launch)
//   K2: U[vox][256] = W5 . feat_u(:,vox)  (layer-5 hoist), S[vox] = b5 . feat_u
//   K3: per 32-query block: L1 fp32 -> L2,L3,L4 via mfma_f32_16x16x32_bf16
//       with 3-term hi/lo split -> out[q] = h4 . U[vox] + S[vox]
// ---------------------------------------------------------------------------

#define FPC (34*34*34)   // 39304
#define FPD (34*34)      // 1156

typedef __bf16 v8bf  __attribute__((ext_vector_type(8)));
typedef float  f32x4 __attribute__((ext_vector_type(4)));

#define MFMA16(a,b,c) __builtin_amdgcn_mfma_f32_16x16x32_bf16((a),(b),(c),0,0,0)

// ---------------- K1: conv encoder ----------------
__global__ void conv_enc_kernel(const float* __restrict__ inp,
                                const float* __restrict__ Wenc,
                                const float* __restrict__ benc,
                                float* __restrict__ featp)
{
    __shared__ float wl[432];
    __shared__ float bl[16];
    int t = threadIdx.x;
    for (int k = t; k < 432; k += 256) wl[k] = Wenc[k];
    if (t < 16) bl[t] = benc[t];
    __syncthreads();

    int vid = blockIdx.x * 256 + t;
    int d = vid >> 10, h = (vid >> 5) & 31, w = vid & 31;

    float v[27];
    #pragma unroll
    for (int dz = 0; dz < 3; dz++)
      #pragma unroll
      for (int dy = 0; dy < 3; dy++)
        #pragma unroll
        for (int dx = 0; dx < 3; dx++) {
            int zz = d + dz - 1, yy = h + dy - 1, xx = w + dx - 1;
            bool ok = (zz >= 0 && zz < 32 && yy >= 0 && yy < 32 && xx >= 0 && xx < 32);
            v[dz*9 + dy*3 + dx] = ok ? inp[(zz << 10) + (yy << 5) + xx] : 0.0f;
        }

    #pragma unroll
    for (int oc = 0; oc < 16; oc++) {
        float a = bl[oc];
        #pragma unroll
        for (int n = 0; n < 27; n++) a = fmaf(v[n], wl[oc*27 + n], a);
        featp[oc*FPC + (d+1)*FPD + (h+1)*34 + (w+1)] = a;
    }
}

// ---------------- Kp: weight transpose + bf16 split ----------------
// Wt layout: [layer][plane][m][k], plane 0 = hi, plane 1 = lo (65536 elems each)
__global__ void prep_weights_kernel(const float* __restrict__ W2,
                                    const float* __restrict__ W3,
                                    const float* __restrict__ W4,
                                    __bf16* __restrict__ Wt)
{
    int l = blockIdx.x >> 8;        // 0..2
    int m = blockIdx.x & 255;
    const float* W = (l == 0) ? W2 : (l == 1) ? W3 : W4;
    int k = threadIdx.x;
    float w = W[k*256 + m];         // W is [k][m]; Wt is [m][k]
    __bf16 hi = (__bf16)w;
    __bf16 lo = (__bf16)(w - (float)hi);
    __bf16* base = Wt + (size_t)l * 131072;
    base[m*256 + k]         = hi;
    base[65536 + m*256 + k] = lo;
}

// ---------------- K2: U / s precompute ----------------
__global__ void u_precompute_kernel(const float* __restrict__ featp,
                                    const float* __restrict__ W5,   // [256][432]
                                    const float* __restrict__ b5,   // [432]
                                    float* __restrict__ U,          // [32768][256]
                                    float* __restrict__ S)          // [32768]
{
    __shared__ float fu[432*32];
    int t = threadIdx.x;
    int d = blockIdx.x >> 5, h = blockIdx.x & 31;

    int kk0 = t >> 5;
    int vv  = t & 31;
    for (int kb = 0; kb < 54; kb++) {
        int k = kb*8 + kk0;
        int c = k / 27, n = k % 27;
        int i = n / 9, j = (n / 3) % 3, x = n % 3;
        fu[k*32 + vv] = featp[c*FPC + (d + i)*FPD + (h + j)*34 + (vv + x)];
    }
    __syncthreads();

    int jt = t & 63, vt = t >> 6;
    int j0 = jt * 4, v0 = vt * 8;
    float acc[8][4];
    #pragma unroll
    for (int a = 0; a < 8; a++)
        #pragma unroll
        for (int b = 0; b < 4; b++) acc[a][b] = 0.0f;

    for (int k = 0; k < 432; k += 4) {
        float4 w0 = *(const float4*)(W5 + (size_t)(j0 + 0)*432 + k);
        float4 w1 = *(const float4*)(W5 + (size_t)(j0 + 1)*432 + k);
        float4 w2 = *(const float4*)(W5 + (size_t)(j0 + 2)*432 + k);
        float4 w3 = *(const float4*)(W5 + (size_t)(j0 + 3)*432 + k);
        float wr[4][4] = {{w0.x,w0.y,w0.z,w0.w},{w1.x,w1.y,w1.z,w1.w},
                          {w2.x,w2.y,w2.z,w2.w},{w3.x,w3.y,w3.z,w3.w}};
        #pragma unroll
        for (int u = 0; u < 4; u++) {
            float4 a0 = *(const float4*)(fu + (k + u)*32 + v0);
            float4 a1 = *(const float4*)(fu + (k + u)*32 + v0 + 4);
            float av[8] = {a0.x,a0.y,a0.z,a0.w,a1.x,a1.y,a1.z,a1.w};
            #pragma unroll
            for (int v = 0; v < 8; v++) {
                acc[v][0] = fmaf(av[v], wr[0][u], acc[v][0]);
                acc[v][1] = fmaf(av[v], wr[1][u], acc[v][1]);
                acc[v][2] = fmaf(av[v], wr[2][u], acc[v][2]);
                acc[v][3] = fmaf(av[v], wr[3][u], acc[v][3]);
            }
        }
    }

    size_t voxbase = (size_t)blockIdx.x * 32;
    #pragma unroll
    for (int v = 0; v < 8; v++) {
        *(float4*)(U + (voxbase + v0 + v)*256 + j0) =
            make_float4(acc[v][0], acc[v][1], acc[v][2], acc[v][3]);
    }

    if (t < 32) {
        float s = 0.0f;
        for (int k = 0; k < 432; k++) s = fmaf(b5[k], fu[k*32 + t], s);
        S[voxbase + t] = s;
    }
}

// ---------------- K3: fused query MLP (MFMA) ----------------
// LDS activation layout: [query q][k] bf16, 256 per row, XOR swizzle on the
// element index: phys = q*256 + (k ^ ((q&7)<<3)).  B-frag (ds_read_b128) and
// epilogue scalar writes are then conflict-free (<=2-way).
template<int LAST>
__device__ __forceinline__
void layer_mfma(const __bf16* __restrict__ Wly,   // hi plane; lo plane at +65536
                const float* __restrict__ bias,
                const __bf16* __restrict__ src_hi, const __bf16* __restrict__ src_lo,
                __bf16* __restrict__ dst_hi, __bf16* __restrict__ dst_lo,
                float* __restrict__ h4f, int t)
{
    const int l  = t & 63;
    const int wv = t >> 6;          // wave 0..7 -> output rows [32wv, 32wv+32)
    const int m0 = wv << 5;
    const int lr = l & 15;
    const int lk = l >> 4;

    f32x4 acc[2][2];
    #pragma unroll
    for (int ms = 0; ms < 2; ms++) {
        const float* bp = bias + m0 + ms*16 + 4*lk;   // D row = 4*(l>>4)+reg  (m89)
        f32x4 bv;
        bv[0] = bp[0]; bv[1] = bp[1]; bv[2] = bp[2]; bv[3] = bp[3];
        acc[ms][0] = bv;
        acc[ms][1] = bv;
    }

    const int swz = (lr & 7) << 3;  // (j&7)<<3 is equal for j=lr and j=16+lr

    #pragma unroll 2
    for (int k0 = 0; k0 < 256; k0 += 32) {
        const int kb = k0 + 8*lk;   // A/B frag: k = 8*(l>>4) + e
        v8bf Ah0 = *(const v8bf*)(Wly +         (m0 +      lr)*256 + kb);
        v8bf Al0 = *(const v8bf*)(Wly + 65536 + (m0 +      lr)*256 + kb);
        v8bf Ah1 = *(const v8bf*)(Wly +         (m0 + 16 + lr)*256 + kb);
        v8bf Al1 = *(const v8bf*)(Wly + 65536 + (m0 + 16 + lr)*256 + kb);
        const int kx = kb ^ swz;
        v8bf Bh0 = *(const v8bf*)(src_hi +       lr *256 + kx);
        v8bf Bl0 = *(const v8bf*)(src_lo +       lr *256 + kx);
        v8bf Bh1 = *(const v8bf*)(src_hi + (16 + lr)*256 + kx);
        v8bf Bl1 = *(const v8bf*)(src_lo + (16 + lr)*256 + kx);

        acc[0][0] = MFMA16(Ah0, Bh0, acc[0][0]);
        acc[0][0] = MFMA16(Ah0, Bl0, acc[0][0]);
        acc[0][0] = MFMA16(Al0, Bh0, acc[0][0]);
        acc[0][1] = MFMA16(Ah0, Bh1, acc[0][1]);
        acc[0][1] = MFMA16(Ah0, Bl1, acc[0][1]);
        acc[0][1] = MFMA16(Al0, Bh1, acc[0][1]);
        acc[1][0] = MFMA16(Ah1, Bh0, acc[1][0]);
        acc[1][0] = MFMA16(Ah1, Bl0, acc[1][0]);
        acc[1][0] = MFMA16(Al1, Bh0, acc[1][0]);
        acc[1][1] = MFMA16(Ah1, Bh1, acc[1][1]);
        acc[1][1] = MFMA16(Ah1, Bl1, acc[1][1]);
        acc[1][1] = MFMA16(Al1, Bh1, acc[1][1]);
    }

    #pragma unroll
    for (int ms = 0; ms < 2; ms++)
      #pragma unroll
      for (int nj = 0; nj < 2; nj++) {
        const int j  = nj*16 + lr;          // query (D col = lane&15)
        const int mb = m0 + ms*16 + 4*lk;   // D row = 4*(l>>4)+reg
        if (LAST) {
            f32x4 v;
            v[0] = fmaxf(acc[ms][nj][0], 0.0f);
            v[1] = fmaxf(acc[ms][nj][1], 0.0f);
            v[2] = fmaxf(acc[ms][nj][2], 0.0f);
            v[3] = fmaxf(acc[ms][nj][3], 0.0f);
            *(f32x4*)(h4f + j*256 + (mb ^ ((j & 7) << 2))) = v;   // fp32 swizzle
        } else {
            #pragma unroll
            for (int r = 0; r < 4; r++) {
                float a = fmaxf(acc[ms][nj][r], 0.0f);
                __bf16 hi = (__bf16)a;
                __bf16 lo = (__bf16)(a - (float)hi);
                int idx = j*256 + ((mb + r) ^ ((j & 7) << 3));
                dst_hi[idx] = hi;
                dst_lo[idx] = lo;
            }
        }
      }
}

__global__ __launch_bounds__(512, 4)
void query_mfma_kernel(const float* __restrict__ coord, const float* __restrict__ cell,
                       const float* __restrict__ W1, const float* __restrict__ b1,
                       const __bf16* __restrict__ Wt,
                       const float* __restrict__ b2, const float* __restrict__ b3,
                       const float* __restrict__ b4,
                       const float* __restrict__ U, const float* __restrict__ S,
                       float* __restrict__ out)
{
    __shared__ __align__(16) char smem[65536];
    __bf16* hA_hi = (__bf16*)(smem);            // [32][256] bf16
    __bf16* hA_lo = (__bf16*)(smem + 16384);
    __bf16* hB_hi = (__bf16*)(smem + 32768);
    __bf16* hB_lo = (__bf16*)(smem + 49152);
    float*  h4f   = (float*)(smem + 32768);     // [32][256] fp32, over hB (dead h2)
    float*  xS    = (float*)(smem + 32768);     // [4][32], dead before L2 writes hB

    const int t = threadIdx.x;
    const int qbase = blockIdx.x * 32;

    if (t < 32) {
        int gq = qbase + t;
        float c0 = coord[3*gq+0], c1 = coord[3*gq+1], c2 = coord[3*gq+2];
        float e0 = cell[3*gq+0],  e1 = cell[3*gq+1],  e2 = cell[3*gq+2];
        float x0 = c0 - e0*0.5f, x1 = c1 - e1*0.5f, x2 = c2 - e2*0.5f;

        // q_coord: round on UNclipped coord_, all-or-nothing valid mask
        float f0 = rintf(((x0 + 1.0f)*32.0f - 1.0f)*0.5f);
        float f1 = rintf(((x1 + 1.0f)*32.0f - 1.0f)*0.5f);
        float f2 = rintf(((x2 + 1.0f)*32.0f - 1.0f)*0.5f);
        bool valid = (f0 >= 0.0f && f0 < 32.0f &&
                      f1 >= 0.0f && f1 < 32.0f &&
                      f2 >= 0.0f && f2 < 32.0f);
        int i0 = min(max((int)f0, 0), 31);
        int i1 = min(max((int)f1, 0), 31);
        int i2 = min(max((int)f2, 0), 31);
        float qc0 = -0.96875f + 0.0625f*(float)i0;
        float qc1 = -0.96875f + 0.0625f*(float)i1;
        float qc2 = -0.96875f + 0.0625f*(float)i2;
        // ref quirk: fc[:,:,w,:] for w in {0,1,3} gets -1/32 on ALL components
        float adj = (i2 == 0 || i2 == 1 || i2 == 3) ? -0.03125f : 0.0f;
        qc0 += adj; qc1 += adj; qc2 += adj;
        if (!valid) { qc0 = 0.0f; qc1 = 0.0f; qc2 = 0.0f; }

        xS[0*32 + t] = (x0 - qc0)*32.0f;
        xS[1*32 + t] = (x1 - qc1)*32.0f;
        xS[2*32 + t] = (x2 - qc2)*32.0f;
        xS[3*32 + t] = e0 * 16.0f;
    }
    __syncthreads();

    // ----- layer 1: 4 -> 256, fp32 exact, split on store -----
    {
        int q  = t >> 4;            // 0..31
        int jg = (t & 15) << 4;     // 16 neurons per thread
        float x0 = xS[q], x1 = xS[32+q], x2 = xS[64+q], x3 = xS[96+q];
        v8bf hv0, hv1, lv0, lv1;
        #pragma unroll
        for (int i = 0; i < 16; i++) {
            int j = jg + i;
            float a = b1[j];
            a = fmaf(x0, W1[j],       a);
            a = fmaf(x1, W1[256 + j], a);
            a = fmaf(x2, W1[512 + j], a);
            a = fmaf(x3, W1[768 + j], a);
            a = fmaxf(a, 0.0f);
            __bf16 hi = (__bf16)a;
            __bf16 lo = (__bf16)(a - (float)hi);
            if (i < 8) { hv0[i] = hi; lv0[i] = lo; }
            else       { hv1[i-8] = hi; lv1[i-8] = lo; }
        }
        int sw = (q & 7) << 3;
        int base = q * 256;
        *(v8bf*)(hA_hi + base + ( jg      ^ sw)) = hv0;
        *(v8bf*)(hA_hi + base + ((jg + 8) ^ sw)) = hv1;
        *(v8bf*)(hA_lo + base + ( jg      ^ sw)) = lv0;
        *(v8bf*)(hA_lo + base + ((jg + 8) ^ sw)) = lv1;
    }
    __syncthreads();

    layer_mfma<0>(Wt,          b2, hA_hi, hA_lo, hB_hi, hB_lo, nullptr, t);
    __syncthreads();
    layer_mfma<0>(Wt + 131072, b3, hB_hi, hB_lo, hA_hi, hA_lo, nullptr, t);
    __syncthreads();
    layer_mfma<1>(Wt + 262144, b4, hA_hi, hA_lo, nullptr, nullptr, h4f, t);
    __syncthreads();

    // ----- final: out[q] = h4 . U[vox] + S[vox] -----
    {
        int q = t >> 4, part = t & 15;
        int gq = qbase + q;
        float c0 = coord[3*gq+0], c1 = coord[3*gq+1], c2 = coord[3*gq+2];
        float e0 = cell[3*gq+0],  e1 = cell[3*gq+1],  e2 = cell[3*gq+2];
        const float LO = (float)(-1.0 + 1e-6);
        const float HI = (float)( 1.0 - 1e-6);
        float x0 = fminf(fmaxf(c0 - e0*0.5f + 1e-6f, LO), HI);
        float x1 = fminf(fmaxf(c1 - e1*0.5f + 1e-6f, LO), HI);
        float x2 = fminf(fmaxf(c2 - e2*0.5f + 1e-6f, LO), HI);
        int i0 = min(max((int)rintf(((x0 + 1.0f)*32.0f - 1.0f)*0.5f), 0), 31);
        int i1 = min(max((int)rintf(((x1 + 1.0f)*32.0f - 1.0f)*0.5f), 0), 31);
        int i2 = min(max((int)rintf(((x2 + 1.0f)*32.0f - 1.0f)*0.5f), 0), 31);
        int vox = (i0 << 10) + (i1 << 5) + i2;

        const float* Ur = U + (size_t)vox*256 + part*16;
        const float* hrow = h4f + q*256;
        const int sw = (q & 7) << 2;
        float sum = 0.0f;
        #pragma unroll
        for (int i = 0; i < 16; i += 4) {
            float4 u = *(const float4*)(Ur + i);
            f32x4 h = *(const f32x4*)(hrow + ((part*16 + i) ^ sw));
            sum = fmaf(u.x, h[0], sum);
            sum = fmaf(u.y, h[1], sum);
            sum = fmaf(u.z, h[2], sum);
            sum = fmaf(u.w, h[3], sum);
        }
        sum += __shfl_down(sum, 8);
        sum += __shfl_down(sum, 4);
        sum += __shfl_down(sum, 2);
        sum += __shfl_down(sum, 1);
        if (part == 0) out[gq] = sum + S[vox];
    }
}

// ---------------------------------------------------------------------------
extern "C" void kernel_launch(void* const* d_in, const int* in_sizes, int n_in,
                              void* d_out, int out_size, void* d_ws, size_t ws_size,
                              hipStream_t stream)
{
    const float* inp   = (const float*)d_in[0];
    const float* coord = (const float*)d_in[1];
    const float* cell  = (const float*)d_in[2];
    const float* Wenc  = (const float*)d_in[3];
    const float* benc  = (const float*)d_in[4];
    const float* W1 = (const float*)d_in[5];  const float* b1 = (const float*)d_in[6];
    const float* W2 = (const float*)d_in[7];  const float* b2 = (const float*)d_in[8];
    const float* W3 = (const float*)d_in[9];  const float* b3 = (const float*)d_in[10];
    const float* W4 = (const float*)d_in[11]; const float* b4 = (const float*)d_in[12];
    const float* W5 = (const float*)d_in[13]; const float* b5 = (const float*)d_in[14];
    float* out = (float*)d_out;

    char* ws = (char*)d_ws;
    float*  featp = (float*)ws;                        // 2,515,456 B
    float*  U     = (float*)(ws + 2515456);            // 33,554,432 B
    float*  S     = (float*)(ws + 36069888);           // 131,072 B
    __bf16* Wt    = (__bf16*)(ws + 36200960);          // 786,432 B -> total ~37 MB

    hipMemsetAsync(featp, 0, (size_t)16*FPC*sizeof(float), stream);
    conv_enc_kernel<<<128, 256, 0, stream>>>(inp, Wenc, benc, featp);
    prep_weights_kernel<<<768, 256, 0, stream>>>(W2, W3, W4, Wt);
    u_precompute_kernel<<<1024, 256, 0, stream>>>(featp, W5, b5, U, S);
    query_mfma_kernel<<<6250, 512, 0, stream>>>(coord, cell, W1, b1, Wt,
                                                b2, b3, b4, U, S, out);
}

// Round 8
// 811.420 us; speedup vs baseline: 1.7810x; 1.3275x over previous
//
#include <hip/hip_runtime.h>
#include <cstddef>
#include <cstdint>

// ---------------------------------------------------------------------------
// MetaSR fused pipeline, MFMA bf16-split, 64-query blocks.
//   K1: conv encoder -> feat padded [16][34][34][34] (borders zero)
//   Kp: transpose+split W2/W3/W4 -> Wt[m][k] bf16 hi/lo (once per launch)
//   K2: U[vox][256] = W5 . feat_u(:,vox)  (layer-5 hoist), S[vox] = b5 . feat_u
//   K3: per 64-query block: L1 fp32 -> L2,L3,L4 via mfma_f32_16x16x32_bf16
//       3-term hi/lo split, ONE in-place LDS activation buffer (acc in regs
//       across a barrier), A-frag prefetch pipeline, (q&15)<<3 swizzle.
//       -> out[q] = h4 . U[vox] + S[vox]
// ---------------------------------------------------------------------------

#define FPC (34*34*34)   // 39304
#define FPD (34*34)      // 1156

typedef __bf16 v8bf  __attribute__((ext_vector_type(8)));
typedef __bf16 v4bf  __attribute__((ext_vector_type(4)));
typedef float  f32x4 __attribute__((ext_vector_type(4)));

#define MFMA16(a,b,c) __builtin_amdgcn_mfma_f32_16x16x32_bf16((a),(b),(c),0,0,0)

// ---------------- K1: conv encoder ----------------
__global__ void conv_enc_kernel(const float* __restrict__ inp,
                                const float* __restrict__ Wenc,
                                const float* __restrict__ benc,
                                float* __restrict__ featp)
{
    __shared__ float wl[432];
    __shared__ float bl[16];
    int t = threadIdx.x;
    for (int k = t; k < 432; k += 256) wl[k] = Wenc[k];
    if (t < 16) bl[t] = benc[t];
    __syncthreads();

    int vid = blockIdx.x * 256 + t;
    int d = vid >> 10, h = (vid >> 5) & 31, w = vid & 31;

    float v[27];
    #pragma unroll
    for (int dz = 0; dz < 3; dz++)
      #pragma unroll
      for (int dy = 0; dy < 3; dy++)
        #pragma unroll
        for (int dx = 0; dx < 3; dx++) {
            int zz = d + dz - 1, yy = h + dy - 1, xx = w + dx - 1;
            bool ok = (zz >= 0 && zz < 32 && yy >= 0 && yy < 32 && xx >= 0 && xx < 32);
            v[dz*9 + dy*3 + dx] = ok ? inp[(zz << 10) + (yy << 5) + xx] : 0.0f;
        }

    #pragma unroll
    for (int oc = 0; oc < 16; oc++) {
        float a = bl[oc];
        #pragma unroll
        for (int n = 0; n < 27; n++) a = fmaf(v[n], wl[oc*27 + n], a);
        featp[oc*FPC + (d+1)*FPD + (h+1)*34 + (w+1)] = a;
    }
}

// ---------------- Kp: weight transpose + bf16 split ----------------
__global__ void prep_weights_kernel(const float* __restrict__ W2,
                                    const float* __restrict__ W3,
                                    const float* __restrict__ W4,
                                    __bf16* __restrict__ Wt)
{
    int l = blockIdx.x >> 8;        // 0..2
    int m = blockIdx.x & 255;
    const float* W = (l == 0) ? W2 : (l == 1) ? W3 : W4;
    int k = threadIdx.x;
    float w = W[k*256 + m];         // W is [k][m]; Wt is [m][k]
    __bf16 hi = (__bf16)w;
    __bf16 lo = (__bf16)(w - (float)hi);
    __bf16* base = Wt + (size_t)l * 131072;
    base[m*256 + k]         = hi;
    base[65536 + m*256 + k] = lo;
}

// ---------------- K2: U / s precompute ----------------
__global__ void u_precompute_kernel(const float* __restrict__ featp,
                                    const float* __restrict__ W5,   // [256][432]
                                    const float* __restrict__ b5,   // [432]
                                    float* __restrict__ U,          // [32768][256]
                                    float* __restrict__ S)          // [32768]
{
    __shared__ float fu[432*32];
    int t = threadIdx.x;
    int d = blockIdx.x >> 5, h = blockIdx.x & 31;

    int kk0 = t >> 5;
    int vv  = t & 31;
    for (int kb = 0; kb < 54; kb++) {
        int k = kb*8 + kk0;
        int c = k / 27, n = k % 27;
        int i = n / 9, j = (n / 3) % 3, x = n % 3;
        fu[k*32 + vv] = featp[c*FPC + (d + i)*FPD + (h + j)*34 + (vv + x)];
    }
    __syncthreads();

    int jt = t & 63, vt = t >> 6;
    int j0 = jt * 4, v0 = vt * 8;
    float acc[8][4];
    #pragma unroll
    for (int a = 0; a < 8; a++)
        #pragma unroll
        for (int b = 0; b < 4; b++) acc[a][b] = 0.0f;

    for (int k = 0; k < 432; k += 4) {
        float4 w0 = *(const float4*)(W5 + (size_t)(j0 + 0)*432 + k);
        float4 w1 = *(const float4*)(W5 + (size_t)(j0 + 1)*432 + k);
        float4 w2 = *(const float4*)(W5 + (size_t)(j0 + 2)*432 + k);
        float4 w3 = *(const float4*)(W5 + (size_t)(j0 + 3)*432 + k);
        float wr[4][4] = {{w0.x,w0.y,w0.z,w0.w},{w1.x,w1.y,w1.z,w1.w},
                          {w2.x,w2.y,w2.z,w2.w},{w3.x,w3.y,w3.z,w3.w}};
        #pragma unroll
        for (int u = 0; u < 4; u++) {
            float4 a0 = *(const float4*)(fu + (k + u)*32 + v0);
            float4 a1 = *(const float4*)(fu + (k + u)*32 + v0 + 4);
            float av[8] = {a0.x,a0.y,a0.z,a0.w,a1.x,a1.y,a1.z,a1.w};
            #pragma unroll
            for (int v = 0; v < 8; v++) {
                acc[v][0] = fmaf(av[v], wr[0][u], acc[v][0]);
                acc[v][1] = fmaf(av[v], wr[1][u], acc[v][1]);
                acc[v][2] = fmaf(av[v], wr[2][u], acc[v][2]);
                acc[v][3] = fmaf(av[v], wr[3][u], acc[v][3]);
            }
        }
    }

    size_t voxbase = (size_t)blockIdx.x * 32;
    #pragma unroll
    for (int v = 0; v < 8; v++) {
        *(float4*)(U + (voxbase + v0 + v)*256 + j0) =
            make_float4(acc[v][0], acc[v][1], acc[v][2], acc[v][3]);
    }

    if (t < 32) {
        float s = 0.0f;
        for (int k = 0; k < 432; k++) s = fmaf(b5[k], fu[k*32 + t], s);
        S[voxbase + t] = s;
    }
}

// ---------------- K3: fused query MLP (MFMA, 64 q/block) ----------------
// Activation LDS: ONE buffer, hi plane [64][256] bf16 + lo plane.
// Swizzle: phys elem = q*256 + (k ^ ((q&15)<<3)).  With B-frag reads
// (ds_read_b128) this gives exactly 4 lanes per 16B slot = conflict-free.
template<int LAST>
__device__ __forceinline__
void layer64(const __bf16* __restrict__ Wly,   // hi plane; lo plane at +65536
             const float* __restrict__ bias,
             __bf16* act_hi, __bf16* act_lo, float* h4f, int t)
{
    const int l  = t & 63;
    const int wv = t >> 6;          // wave 0..7 -> output rows [32wv, 32wv+32)
    const int m0 = wv << 5;
    const int lr = l & 15;
    const int lk = l >> 4;

    f32x4 acc[2][4];
    {
        f32x4 bv0 = *(const f32x4*)(bias + m0 + 4*lk);        // D row = 4*(l>>4)+reg
        f32x4 bv1 = *(const f32x4*)(bias + m0 + 16 + 4*lk);
        #pragma unroll
        for (int nj = 0; nj < 4; nj++) { acc[0][nj] = bv0; acc[1][nj] = bv1; }
    }

    const __bf16* w0 = Wly + (m0 + lr)*256;        // row m0+lr      (hi; lo at +65536)
    const __bf16* w1 = Wly + (m0 + 16 + lr)*256;   // row m0+16+lr

    v8bf cA0 = *(const v8bf*)(w0 + 8*lk);
    v8bf cA1 = *(const v8bf*)(w0 + 65536 + 8*lk);
    v8bf cA2 = *(const v8bf*)(w1 + 8*lk);
    v8bf cA3 = *(const v8bf*)(w1 + 65536 + 8*lk);

    #pragma unroll
    for (int k0 = 0; k0 < 8; k0++) {
        v8bf nA0, nA1, nA2, nA3;
        if (k0 < 7) {                   // prefetch next k-step's A-frags
            const int kbn = (k0+1)*32 + 8*lk;
            nA0 = *(const v8bf*)(w0 + kbn);
            nA1 = *(const v8bf*)(w0 + 65536 + kbn);
            nA2 = *(const v8bf*)(w1 + kbn);
            nA3 = *(const v8bf*)(w1 + 65536 + kbn);
        }
        const int kb = k0*32 + 8*lk;
        const int kx = kb ^ (lr << 3);  // q&15 == lr for every nj
        #pragma unroll
        for (int nj = 0; nj < 4; nj++) {
            const int q = nj*16 + lr;
            v8bf Bh = *(const v8bf*)(act_hi + q*256 + kx);
            v8bf Bl = *(const v8bf*)(act_lo + q*256 + kx);
            acc[0][nj] = MFMA16(cA0, Bh, acc[0][nj]);
            acc[0][nj] = MFMA16(cA0, Bl, acc[0][nj]);
            acc[0][nj] = MFMA16(cA1, Bh, acc[0][nj]);
            acc[1][nj] = MFMA16(cA2, Bh, acc[1][nj]);
            acc[1][nj] = MFMA16(cA2, Bl, acc[1][nj]);
            acc[1][nj] = MFMA16(cA3, Bh, acc[1][nj]);
        }
        if (k0 < 7) { cA0 = nA0; cA1 = nA1; cA2 = nA2; cA3 = nA3; }
    }

    __syncthreads();                    // all reads of act buffer complete

    #pragma unroll
    for (int ms = 0; ms < 2; ms++)
      #pragma unroll
      for (int nj = 0; nj < 4; nj++) {
        const int q  = nj*16 + lr;          // D col = lane&15 -> query
        const int mb = m0 + ms*16 + 4*lk;   // D row = 4*(l>>4)+reg
        if (LAST) {
            f32x4 v;
            #pragma unroll
            for (int r = 0; r < 4; r++) v[r] = fmaxf(acc[ms][nj][r], 0.0f);
            *(f32x4*)(h4f + q*256 + (mb ^ ((q & 15) << 2))) = v;
        } else {
            v4bf hv, lv;
            #pragma unroll
            for (int r = 0; r < 4; r++) {
                float a = fmaxf(acc[ms][nj][r], 0.0f);
                __bf16 hi = (__bf16)a;
                hv[r] = hi;
                lv[r] = (__bf16)(a - (float)hi);
            }
            const int idx = q*256 + (mb ^ ((q & 15) << 3));
            *(v4bf*)(act_hi + idx) = hv;
            *(v4bf*)(act_lo + idx) = lv;
        }
      }
    __syncthreads();
}

__global__ __launch_bounds__(512, 4)
void query_mfma_kernel(const float* __restrict__ coord, const float* __restrict__ cell,
                       const float* __restrict__ W1, const float* __restrict__ b1,
                       const __bf16* __restrict__ Wt,
                       const float* __restrict__ b2, const float* __restrict__ b3,
                       const float* __restrict__ b4,
                       const float* __restrict__ U, const float* __restrict__ S,
                       float* __restrict__ out)
{
    __shared__ __align__(16) char smem[65536];
    __bf16* act_hi = (__bf16*)(smem);            // [64][256] bf16 (32 KB)
    __bf16* act_lo = (__bf16*)(smem + 32768);    // [64][256] bf16 (32 KB)
    float*  h4f    = (float*)(smem);             // [64][256] fp32 overlay (64 KB)
    float*  xS     = (float*)(smem);             // [4][64] overlay, dead before L1 writes

    const int t = threadIdx.x;
    const int qbase = blockIdx.x * 64;

    if (t < 64) {
        int gq = qbase + t;
        float c0 = coord[3*gq+0], c1 = coord[3*gq+1], c2 = coord[3*gq+2];
        float e0 = cell[3*gq+0],  e1 = cell[3*gq+1],  e2 = cell[3*gq+2];
        float x0 = c0 - e0*0.5f, x1 = c1 - e1*0.5f, x2 = c2 - e2*0.5f;

        // q_coord: round on UNclipped coord_, all-or-nothing valid mask
        float f0 = rintf(((x0 + 1.0f)*32.0f - 1.0f)*0.5f);
        float f1 = rintf(((x1 + 1.0f)*32.0f - 1.0f)*0.5f);
        float f2 = rintf(((x2 + 1.0f)*32.0f - 1.0f)*0.5f);
        bool valid = (f0 >= 0.0f && f0 < 32.0f &&
                      f1 >= 0.0f && f1 < 32.0f &&
                      f2 >= 0.0f && f2 < 32.0f);
        int i0 = min(max((int)f0, 0), 31);
        int i1 = min(max((int)f1, 0), 31);
        int i2 = min(max((int)f2, 0), 31);
        float qc0 = -0.96875f + 0.0625f*(float)i0;
        float qc1 = -0.96875f + 0.0625f*(float)i1;
        float qc2 = -0.96875f + 0.0625f*(float)i2;
        // ref quirk: fc[:,:,w,:] for w in {0,1,3} gets -1/32 on ALL components
        float adj = (i2 == 0 || i2 == 1 || i2 == 3) ? -0.03125f : 0.0f;
        qc0 += adj; qc1 += adj; qc2 += adj;
        if (!valid) { qc0 = 0.0f; qc1 = 0.0f; qc2 = 0.0f; }

        xS[0*64 + t] = (x0 - qc0)*32.0f;
        xS[1*64 + t] = (x1 - qc1)*32.0f;
        xS[2*64 + t] = (x2 - qc2)*32.0f;
        xS[3*64 + t] = e0 * 16.0f;           // r_rev = cell0 * (H/2)
    }
    __syncthreads();

    // ----- layer 1: 4 -> 256, fp32 exact, split on store -----
    {
        const int q  = t & 63;
        const int jg = (t >> 6) * 32;        // 32 neurons per thread
        float x0 = xS[q], x1 = xS[64+q], x2 = xS[128+q], x3 = xS[192+q];
        float vals[32];
        #pragma unroll
        for (int i = 0; i < 32; i++) {
            int j = jg + i;
            float a = b1[j];
            a = fmaf(x0, W1[j],       a);
            a = fmaf(x1, W1[256 + j], a);
            a = fmaf(x2, W1[512 + j], a);
            a = fmaf(x3, W1[768 + j], a);
            vals[i] = fmaxf(a, 0.0f);
        }
        __syncthreads();                     // xS now dead
        const int sw = (q & 15) << 3;
        #pragma unroll
        for (int g = 0; g < 4; g++) {
            v8bf hv, lv;
            #pragma unroll
            for (int e = 0; e < 8; e++) {
                float a = vals[g*8 + e];
                __bf16 hi = (__bf16)a;
                hv[e] = hi;
                lv[e] = (__bf16)(a - (float)hi);
            }
            const int idx = q*256 + ((jg + g*8) ^ sw);
            *(v8bf*)(act_hi + idx) = hv;
            *(v8bf*)(act_lo + idx) = lv;
        }
    }
    __syncthreads();

    layer64<0>(Wt,          b2, act_hi, act_lo, nullptr, t);
    layer64<0>(Wt + 131072, b3, act_hi, act_lo, nullptr, t);
    layer64<1>(Wt + 262144, b4, act_hi, act_lo, h4f, t);
    // layer64 ends with __syncthreads(); h4f ready

    // ----- final: out[q] = h4 . U[vox] + S[vox] -----
    {
        const int q = t >> 3, part = t & 7;
        const int gq = qbase + q;
        float c0 = coord[3*gq+0], c1 = coord[3*gq+1], c2 = coord[3*gq+2];
        float e0 = cell[3*gq+0],  e1 = cell[3*gq+1],  e2 = cell[3*gq+2];
        const float LO = (float)(-1.0 + 1e-6);
        const float HI = (float)( 1.0 - 1e-6);
        float x0 = fminf(fmaxf(c0 - e0*0.5f + 1e-6f, LO), HI);
        float x1 = fminf(fmaxf(c1 - e1*0.5f + 1e-6f, LO), HI);
        float x2 = fminf(fmaxf(c2 - e2*0.5f + 1e-6f, LO), HI);
        int i0 = min(max((int)rintf(((x0 + 1.0f)*32.0f - 1.0f)*0.5f), 0), 31);
        int i1 = min(max((int)rintf(((x1 + 1.0f)*32.0f - 1.0f)*0.5f), 0), 31);
        int i2 = min(max((int)rintf(((x2 + 1.0f)*32.0f - 1.0f)*0.5f), 0), 31);
        int vox = (i0 << 10) + (i1 << 5) + i2;

        const float* Ur   = U + (size_t)vox*256 + part*32;
        const float* hrow = h4f + q*256;
        const int sw = (q & 15) << 2;
        float sum = 0.0f;
        #pragma unroll
        for (int i = 0; i < 32; i += 4) {
            float4 u = *(const float4*)(Ur + i);
            f32x4 h = *(const f32x4*)(hrow + ((part*32 + i) ^ sw));
            sum = fmaf(u.x, h[0], sum);
            sum = fmaf(u.y, h[1], sum);
            sum = fmaf(u.z, h[2], sum);
            sum = fmaf(u.w, h[3], sum);
        }
        sum += __shfl_down(sum, 4);
        sum += __shfl_down(sum, 2);
        sum += __shfl_down(sum, 1);
        if (part == 0) out[gq] = sum + S[vox];
    }
}

// ---------------------------------------------------------------------------
extern "C" void kernel_launch(void* const* d_in, const int* in_sizes, int n_in,
                              void* d_out, int out_size, void* d_ws, size_t ws_size,
                              hipStream_t stream)
{
    const float* inp   = (const float*)d_in[0];
    const float* coord = (const float*)d_in[1];
    const float* cell  = (const float*)d_in[2];
    const float* Wenc  = (const float*)d_in[3];
    const float* benc  = (const float*)d_in[4];
    const float* W1 = (const float*)d_in[5];  const float* b1 = (const float*)d_in[6];
    const float* W2 = (const float*)d_in[7];  const float* b2 = (const float*)d_in[8];
    const float* W3 = (const float*)d_in[9];  const float* b3 = (const float*)d_in[10];
    const float* W4 = (const float*)d_in[11]; const float* b4 = (const float*)d_in[12];
    const float* W5 = (const float*)d_in[13]; const float* b5 = (const float*)d_in[14];
    float* out = (float*)d_out;

    char* ws = (char*)d_ws;
    float*  featp = (float*)ws;                        // 2,515,456 B
    float*  U     = (float*)(ws + 2515456);            // 33,554,432 B
    float*  S     = (float*)(ws + 36069888);           // 131,072 B
    __bf16* Wt    = (__bf16*)(ws + 36200960);          // 786,432 B -> total ~37 MB

    hipMemsetAsync(featp, 0, (size_t)16*FPC*sizeof(float), stream);
    conv_enc_kernel<<<128, 256, 0, stream>>>(inp, Wenc, benc, featp);
    prep_weights_kernel<<<768, 256, 0, stream>>>(W2, W3, W4, Wt);
    u_precompute_kernel<<<1024, 256, 0, stream>>>(featp, W5, b5, U, S);
    query_mfma_kernel<<<3125, 512, 0, stream>>>(coord, cell, W1, b1, Wt,
                                                b2, b3, b4, U, S, out);
}

// Round 11
// 527.205 us; speedup vs baseline: 2.7411x; 1.5391x over previous
//
#include <hip/hip_runtime.h>
#include <cstddef>
#include <cstdint>

// ---------------------------------------------------------------------------
// MetaSR fused pipeline, MFMA bf16-split everywhere.
//   K1:  conv encoder -> feat padded [16][34][34][34] (borders zero)
//   Kp:  transpose+split W2/W3/W4 -> Wt[m][k] bf16 hi/lo
//   Kp5: split+pad W5 [256][432] -> W5t [256][448] bf16 hi/lo (k>=432 zero)
//   K2:  u_mfma: U[vox][256] = W5 . feat_u(:,vox) via mfma_16x16x32_bf16,
//        3-term hi/lo split, 64 vox/block, K in two halves of 224 staged in
//        a [64][256]-slot swizzled LDS buffer (64 KB), A-frag prefetch.
//   K2b: s_kernel: S[vox] = b5 . feat_u(:,vox)  (fp32, coalesced)
//   K3:  query MLP (unchanged from R5/R8 measured version)
// ---------------------------------------------------------------------------

#define FPC (34*34*34)   // 39304
#define FPD (34*34)      // 1156

typedef __bf16 v8bf  __attribute__((ext_vector_type(8)));
typedef __bf16 v4bf  __attribute__((ext_vector_type(4)));
typedef float  f32x4 __attribute__((ext_vector_type(4)));

#define MFMA16(a,b,c) __builtin_amdgcn_mfma_f32_16x16x32_bf16((a),(b),(c),0,0,0)
#define W5T_LO 114688   // 256*448, lo-plane offset in W5t

// ---------------- K1: conv encoder ----------------
__global__ void conv_enc_kernel(const float* __restrict__ inp,
                                const float* __restrict__ Wenc,
                                const float* __restrict__ benc,
                                float* __restrict__ featp)
{
    __shared__ float wl[432];
    __shared__ float bl[16];
    int t = threadIdx.x;
    for (int k = t; k < 432; k += 256) wl[k] = Wenc[k];
    if (t < 16) bl[t] = benc[t];
    __syncthreads();

    int vid = blockIdx.x * 256 + t;
    int d = vid >> 10, h = (vid >> 5) & 31, w = vid & 31;

    float v[27];
    #pragma unroll
    for (int dz = 0; dz < 3; dz++)
      #pragma unroll
      for (int dy = 0; dy < 3; dy++)
        #pragma unroll
        for (int dx = 0; dx < 3; dx++) {
            int zz = d + dz - 1, yy = h + dy - 1, xx = w + dx - 1;
            bool ok = (zz >= 0 && zz < 32 && yy >= 0 && yy < 32 && xx >= 0 && xx < 32);
            v[dz*9 + dy*3 + dx] = ok ? inp[(zz << 10) + (yy << 5) + xx] : 0.0f;
        }

    #pragma unroll
    for (int oc = 0; oc < 16; oc++) {
        float a = bl[oc];
        #pragma unroll
        for (int n = 0; n < 27; n++) a = fmaf(v[n], wl[oc*27 + n], a);
        featp[oc*FPC + (d+1)*FPD + (h+1)*34 + (w+1)] = a;
    }
}

// ---------------- Kp: MLP weight transpose + bf16 split ----------------
__global__ void prep_weights_kernel(const float* __restrict__ W2,
                                    const float* __restrict__ W3,
                                    const float* __restrict__ W4,
                                    __bf16* __restrict__ Wt)
{
    int l = blockIdx.x >> 8;        // 0..2
    int m = blockIdx.x & 255;
    const float* W = (l == 0) ? W2 : (l == 1) ? W3 : W4;
    int k = threadIdx.x;
    float w = W[k*256 + m];         // W is [k][m]; Wt is [m][k]
    __bf16 hi = (__bf16)w;
    __bf16 lo = (__bf16)(w - (float)hi);
    __bf16* base = Wt + (size_t)l * 131072;
    base[m*256 + k]         = hi;
    base[65536 + m*256 + k] = lo;
}

// ---------------- Kp5: W5 split + pad to 448 ----------------
__global__ void prep_w5_kernel(const float* __restrict__ W5,
                               __bf16* __restrict__ W5t)
{
    int j = blockIdx.x;             // 0..255 output row
    int k = threadIdx.x;            // 0..447
    float w = (k < 432) ? W5[j*432 + k] : 0.0f;
    __bf16 hi = (__bf16)w;
    __bf16 lo = (__bf16)(w - (float)hi);
    W5t[j*448 + k]          = hi;
    W5t[W5T_LO + j*448 + k] = lo;
}

// ---------------- K2: U precompute via MFMA ----------------
// 7 K-steps (224) with A-frag register prefetch; B from swizzled LDS.
__device__ __forceinline__
void mfma7(const __bf16* __restrict__ w0, const __bf16* __restrict__ w1,
           const __bf16* fu_hi, const __bf16* fu_lo,
           int lr, int lk, f32x4 acc[2][4])
{
    v8bf cA0 = *(const v8bf*)(w0 + 8*lk);
    v8bf cA1 = *(const v8bf*)(w0 + W5T_LO + 8*lk);
    v8bf cA2 = *(const v8bf*)(w1 + 8*lk);
    v8bf cA3 = *(const v8bf*)(w1 + W5T_LO + 8*lk);

    #pragma unroll
    for (int ks = 0; ks < 7; ks++) {
        v8bf nA0, nA1, nA2, nA3;
        if (ks < 6) {
            const int kbn = (ks+1)*32 + 8*lk;
            nA0 = *(const v8bf*)(w0 + kbn);
            nA1 = *(const v8bf*)(w0 + W5T_LO + kbn);
            nA2 = *(const v8bf*)(w1 + kbn);
            nA3 = *(const v8bf*)(w1 + W5T_LO + kbn);
        }
        const int kb = ks*32 + 8*lk;
        const int kx = kb ^ (lr << 3);
        #pragma unroll
        for (int nj = 0; nj < 4; nj++) {
            const int q = nj*16 + lr;
            v8bf Bh = *(const v8bf*)(fu_hi + q*256 + kx);
            v8bf Bl = *(const v8bf*)(fu_lo + q*256 + kx);
            acc[0][nj] = MFMA16(cA0, Bh, acc[0][nj]);
            acc[0][nj] = MFMA16(cA0, Bl, acc[0][nj]);
            acc[0][nj] = MFMA16(cA1, Bh, acc[0][nj]);
            acc[1][nj] = MFMA16(cA2, Bh, acc[1][nj]);
            acc[1][nj] = MFMA16(cA2, Bl, acc[1][nj]);
            acc[1][nj] = MFMA16(cA3, Bh, acc[1][nj]);
        }
        if (ks < 6) { cA0 = nA0; cA1 = nA1; cA2 = nA2; cA3 = nA3; }
    }
}

__global__ __launch_bounds__(512, 4)
void u_mfma_kernel(const float* __restrict__ featp,
                   const __bf16* __restrict__ W5t,
                   float* __restrict__ U)
{
    __shared__ __align__(16) char smem[65536];
    __bf16* fu_hi = (__bf16*)smem;            // [64][256] bf16, swizzled
    __bf16* fu_lo = (__bf16*)(smem + 32768);

    const int t   = threadIdx.x;
    const int bid = blockIdx.x;               // 512 blocks, 64 vox each
    const int d   = bid >> 4;
    const int h0  = (bid & 15) << 1;

    // staging identity: this thread's voxel row
    const int vox = t & 63;
    const int vh = vox >> 5, w = vox & 31;
    const int sbase = d*FPD + (h0 + vh)*34 + w;
    const int sw_st = (vox & 15) << 3;

    // MFMA identity
    const int l  = t & 63;
    const int wv = t >> 6;
    const int m0 = wv << 5;
    const int lr = l & 15;
    const int lk = l >> 4;

    f32x4 acc[2][4];
    #pragma unroll
    for (int ms = 0; ms < 2; ms++)
      #pragma unroll
      for (int nj = 0; nj < 4; nj++)
        acc[ms][nj] = (f32x4){0.f, 0.f, 0.f, 0.f};

    for (int half = 0; half < 2; half++) {
        // ---- stage fu[vox][k'] for k' = 0..255 (zeros beyond real K) ----
        #pragma unroll
        for (int loop = 0; loop < 4; loop++) {
            const int k0 = ((t >> 6) + 8*loop) * 8;   // 0,8,...,248
            v8bf hv, lv;
            #pragma unroll
            for (int e = 0; e < 8; e++) {
                const int kg = half*224 + k0 + e;     // global k
                float v = 0.0f;
                if (k0 + e < 224 && kg < 432) {
                    const int c  = (kg*4855) >> 17;       // kg/27
                    const int n  = kg - c*27;
                    const int i  = (n*57) >> 9;           // n/9
                    const int m9 = n - 9*i;
                    const int j  = (m9*86) >> 8;          // m9/3
                    const int x  = m9 - 3*j;
                    v = featp[c*FPC + i*FPD + j*34 + x + sbase];
                }
                __bf16 hi = (__bf16)v;
                hv[e] = hi;
                lv[e] = (__bf16)(v - (float)hi);
            }
            const int idx = vox*256 + (k0 ^ sw_st);
            *(v8bf*)(fu_hi + idx) = hv;
            *(v8bf*)(fu_lo + idx) = lv;
        }
        __syncthreads();

        // ---- MFMA over this half's 224 K ----
        const __bf16* w0 = W5t + (m0 + lr)*448      + half*224;
        const __bf16* w1 = W5t + (m0 + 16 + lr)*448 + half*224;
        mfma7(w0, w1, fu_hi, fu_lo, lr, lk, acc);
        __syncthreads();                      // reads done before restage
    }

    // ---- write U[vox][m] ----
    const size_t voxbase = (size_t)bid * 64;
    #pragma unroll
    for (int ms = 0; ms < 2; ms++)
      #pragma unroll
      for (int nj = 0; nj < 4; nj++) {
        const int q  = nj*16 + lr;            // D col = lane&15 -> voxel
        const int mb = m0 + ms*16 + 4*lk;     // D row = 4*(l>>4)+reg
        *(f32x4*)(U + (voxbase + q)*256 + mb) = acc[ms][nj];
      }
}

// ---------------- K2b: S[vox] = b5 . feat_u(:,vox) ----------------
__global__ void s_kernel(const float* __restrict__ featp,
                         const float* __restrict__ b5,
                         float* __restrict__ S)
{
    __shared__ float b5l[432];
    const int t = threadIdx.x;
    for (int k = t; k < 432; k += 256) b5l[k] = b5[k];
    __syncthreads();

    const int vox = blockIdx.x * 256 + t;
    const int d = vox >> 10, h = (vox >> 5) & 31, w = vox & 31;
    const int base = d*FPD + h*34 + w;

    float a0 = 0.f, a1 = 0.f, a2 = 0.f, a3 = 0.f;
    for (int c = 0; c < 16; c++) {
        const float* fp = featp + c*FPC + base;
        const float* bp = b5l + c*27;
        #pragma unroll
        for (int n = 0; n < 27; n++) {
            const int i = n/9, j = (n/3)%3, x = n%3;   // compile-time
            float v = fp[i*FPD + j*34 + x];
            if ((n & 3) == 0)      a0 = fmaf(bp[n], v, a0);
            else if ((n & 3) == 1) a1 = fmaf(bp[n], v, a1);
            else if ((n & 3) == 2) a2 = fmaf(bp[n], v, a2);
            else                   a3 = fmaf(bp[n], v, a3);
        }
    }
    S[vox] = ((a0 + a1) + (a2 + a3));
}

// ---------------- K3: fused query MLP (MFMA, 64 q/block) ----------------
// (unchanged from the R8-measured kernel)
template<int LAST>
__device__ __forceinline__
void layer64(const __bf16* __restrict__ Wly,   // hi plane; lo plane at +65536
             const float* __restrict__ bias,
             __bf16* act_hi, __bf16* act_lo, float* h4f, int t)
{
    const int l  = t & 63;
    const int wv = t >> 6;
    const int m0 = wv << 5;
    const int lr = l & 15;
    const int lk = l >> 4;

    f32x4 acc[2][4];
    {
        f32x4 bv0 = *(const f32x4*)(bias + m0 + 4*lk);
        f32x4 bv1 = *(const f32x4*)(bias + m0 + 16 + 4*lk);
        #pragma unroll
        for (int nj = 0; nj < 4; nj++) { acc[0][nj] = bv0; acc[1][nj] = bv1; }
    }

    const __bf16* w0 = Wly + (m0 + lr)*256;
    const __bf16* w1 = Wly + (m0 + 16 + lr)*256;

    v8bf cA0 = *(const v8bf*)(w0 + 8*lk);
    v8bf cA1 = *(const v8bf*)(w0 + 65536 + 8*lk);
    v8bf cA2 = *(const v8bf*)(w1 + 8*lk);
    v8bf cA3 = *(const v8bf*)(w1 + 65536 + 8*lk);

    #pragma unroll
    for (int k0 = 0; k0 < 8; k0++) {
        v8bf nA0, nA1, nA2, nA3;
        if (k0 < 7) {
            const int kbn = (k0+1)*32 + 8*lk;
            nA0 = *(const v8bf*)(w0 + kbn);
            nA1 = *(const v8bf*)(w0 + 65536 + kbn);
            nA2 = *(const v8bf*)(w1 + kbn);
            nA3 = *(const v8bf*)(w1 + 65536 + kbn);
        }
        const int kb = k0*32 + 8*lk;
        const int kx = kb ^ (lr << 3);
        #pragma unroll
        for (int nj = 0; nj < 4; nj++) {
            const int q = nj*16 + lr;
            v8bf Bh = *(const v8bf*)(act_hi + q*256 + kx);
            v8bf Bl = *(const v8bf*)(act_lo + q*256 + kx);
            acc[0][nj] = MFMA16(cA0, Bh, acc[0][nj]);
            acc[0][nj] = MFMA16(cA0, Bl, acc[0][nj]);
            acc[0][nj] = MFMA16(cA1, Bh, acc[0][nj]);
            acc[1][nj] = MFMA16(cA2, Bh, acc[1][nj]);
            acc[1][nj] = MFMA16(cA2, Bl, acc[1][nj]);
            acc[1][nj] = MFMA16(cA3, Bh, acc[1][nj]);
        }
        if (k0 < 7) { cA0 = nA0; cA1 = nA1; cA2 = nA2; cA3 = nA3; }
    }

    __syncthreads();

    #pragma unroll
    for (int ms = 0; ms < 2; ms++)
      #pragma unroll
      for (int nj = 0; nj < 4; nj++) {
        const int q  = nj*16 + lr;
        const int mb = m0 + ms*16 + 4*lk;
        if (LAST) {
            f32x4 v;
            #pragma unroll
            for (int r = 0; r < 4; r++) v[r] = fmaxf(acc[ms][nj][r], 0.0f);
            *(f32x4*)(h4f + q*256 + (mb ^ ((q & 15) << 2))) = v;
        } else {
            v4bf hv, lv;
            #pragma unroll
            for (int r = 0; r < 4; r++) {
                float a = fmaxf(acc[ms][nj][r], 0.0f);
                __bf16 hi = (__bf16)a;
                hv[r] = hi;
                lv[r] = (__bf16)(a - (float)hi);
            }
            const int idx = q*256 + (mb ^ ((q & 15) << 3));
            *(v4bf*)(act_hi + idx) = hv;
            *(v4bf*)(act_lo + idx) = lv;
        }
      }
    __syncthreads();
}

__global__ __launch_bounds__(512, 4)
void query_mfma_kernel(const float* __restrict__ coord, const float* __restrict__ cell,
                       const float* __restrict__ W1, const float* __restrict__ b1,
                       const __bf16* __restrict__ Wt,
                       const float* __restrict__ b2, const float* __restrict__ b3,
                       const float* __restrict__ b4,
                       const float* __restrict__ U, const float* __restrict__ S,
                       float* __restrict__ out)
{
    __shared__ __align__(16) char smem[65536];
    __bf16* act_hi = (__bf16*)(smem);
    __bf16* act_lo = (__bf16*)(smem + 32768);
    float*  h4f    = (float*)(smem);
    float*  xS     = (float*)(smem);

    const int t = threadIdx.x;
    const int qbase = blockIdx.x * 64;

    if (t < 64) {
        int gq = qbase + t;
        float c0 = coord[3*gq+0], c1 = coord[3*gq+1], c2 = coord[3*gq+2];
        float e0 = cell[3*gq+0],  e1 = cell[3*gq+1],  e2 = cell[3*gq+2];
        float x0 = c0 - e0*0.5f, x1 = c1 - e1*0.5f, x2 = c2 - e2*0.5f;

        float f0 = rintf(((x0 + 1.0f)*32.0f - 1.0f)*0.5f);
        float f1 = rintf(((x1 + 1.0f)*32.0f - 1.0f)*0.5f);
        float f2 = rintf(((x2 + 1.0f)*32.0f - 1.0f)*0.5f);
        bool valid = (f0 >= 0.0f && f0 < 32.0f &&
                      f1 >= 0.0f && f1 < 32.0f &&
                      f2 >= 0.0f && f2 < 32.0f);
        int i0 = min(max((int)f0, 0), 31);
        int i1 = min(max((int)f1, 0), 31);
        int i2 = min(max((int)f2, 0), 31);
        float qc0 = -0.96875f + 0.0625f*(float)i0;
        float qc1 = -0.96875f + 0.0625f*(float)i1;
        float qc2 = -0.96875f + 0.0625f*(float)i2;
        float adj = (i2 == 0 || i2 == 1 || i2 == 3) ? -0.03125f : 0.0f;
        qc0 += adj; qc1 += adj; qc2 += adj;
        if (!valid) { qc0 = 0.0f; qc1 = 0.0f; qc2 = 0.0f; }

        xS[0*64 + t] = (x0 - qc0)*32.0f;
        xS[1*64 + t] = (x1 - qc1)*32.0f;
        xS[2*64 + t] = (x2 - qc2)*32.0f;
        xS[3*64 + t] = e0 * 16.0f;
    }
    __syncthreads();

    {
        const int q  = t & 63;
        const int jg = (t >> 6) * 32;
        float x0 = xS[q], x1 = xS[64+q], x2 = xS[128+q], x3 = xS[192+q];
        float vals[32];
        #pragma unroll
        for (int i = 0; i < 32; i++) {
            int j = jg + i;
            float a = b1[j];
            a = fmaf(x0, W1[j],       a);
            a = fmaf(x1, W1[256 + j], a);
            a = fmaf(x2, W1[512 + j], a);
            a = fmaf(x3, W1[768 + j], a);
            vals[i] = fmaxf(a, 0.0f);
        }
        __syncthreads();
        const int sw = (q & 15) << 3;
        #pragma unroll
        for (int g = 0; g < 4; g++) {
            v8bf hv, lv;
            #pragma unroll
            for (int e = 0; e < 8; e++) {
                float a = vals[g*8 + e];
                __bf16 hi = (__bf16)a;
                hv[e] = hi;
                lv[e] = (__bf16)(a - (float)hi);
            }
            const int idx = q*256 + ((jg + g*8) ^ sw);
            *(v8bf*)(act_hi + idx) = hv;
            *(v8bf*)(act_lo + idx) = lv;
        }
    }
    __syncthreads();

    layer64<0>(Wt,          b2, act_hi, act_lo, nullptr, t);
    layer64<0>(Wt + 131072, b3, act_hi, act_lo, nullptr, t);
    layer64<1>(Wt + 262144, b4, act_hi, act_lo, h4f, t);

    {
        const int q = t >> 3, part = t & 7;
        const int gq = qbase + q;
        float c0 = coord[3*gq+0], c1 = coord[3*gq+1], c2 = coord[3*gq+2];
        float e0 = cell[3*gq+0],  e1 = cell[3*gq+1],  e2 = cell[3*gq+2];
        const float LO = (float)(-1.0 + 1e-6);
        const float HI = (float)( 1.0 - 1e-6);
        float x0 = fminf(fmaxf(c0 - e0*0.5f + 1e-6f, LO), HI);
        float x1 = fminf(fmaxf(c1 - e1*0.5f + 1e-6f, LO), HI);
        float x2 = fminf(fmaxf(c2 - e2*0.5f + 1e-6f, LO), HI);
        int i0 = min(max((int)rintf(((x0 + 1.0f)*32.0f - 1.0f)*0.5f), 0), 31);
        int i1 = min(max((int)rintf(((x1 + 1.0f)*32.0f - 1.0f)*0.5f), 0), 31);
        int i2 = min(max((int)rintf(((x2 + 1.0f)*32.0f - 1.0f)*0.5f), 0), 31);
        int vox = (i0 << 10) + (i1 << 5) + i2;

        const float* Ur   = U + (size_t)vox*256 + part*32;
        const float* hrow = h4f + q*256;
        const int sw = (q & 15) << 2;
        float sum = 0.0f;
        #pragma unroll
        for (int i = 0; i < 32; i += 4) {
            float4 u = *(const float4*)(Ur + i);
            f32x4 h = *(const f32x4*)(hrow + ((part*32 + i) ^ sw));
            sum = fmaf(u.x, h[0], sum);
            sum = fmaf(u.y, h[1], sum);
            sum = fmaf(u.z, h[2], sum);
            sum = fmaf(u.w, h[3], sum);
        }
        sum += __shfl_down(sum, 4);
        sum += __shfl_down(sum, 2);
        sum += __shfl_down(sum, 1);
        if (part == 0) out[gq] = sum + S[vox];
    }
}

// ---------------------------------------------------------------------------
extern "C" void kernel_launch(void* const* d_in, const int* in_sizes, int n_in,
                              void* d_out, int out_size, void* d_ws, size_t ws_size,
                              hipStream_t stream)
{
    const float* inp   = (const float*)d_in[0];
    const float* coord = (const float*)d_in[1];
    const float* cell  = (const float*)d_in[2];
    const float* Wenc  = (const float*)d_in[3];
    const float* benc  = (const float*)d_in[4];
    const float* W1 = (const float*)d_in[5];  const float* b1 = (const float*)d_in[6];
    const float* W2 = (const float*)d_in[7];  const float* b2 = (const float*)d_in[8];
    const float* W3 = (const float*)d_in[9];  const float* b3 = (const float*)d_in[10];
    const float* W4 = (const float*)d_in[11]; const float* b4 = (const float*)d_in[12];
    const float* W5 = (const float*)d_in[13]; const float* b5 = (const float*)d_in[14];
    float* out = (float*)d_out;

    char* ws = (char*)d_ws;
    float*  featp = (float*)ws;                        // 2,515,456 B
    float*  U     = (float*)(ws + 2515456);            // 33,554,432 B
    float*  S     = (float*)(ws + 36069888);           // 131,072 B
    __bf16* Wt    = (__bf16*)(ws + 36200960);          // 786,432 B (MLP)
    __bf16* W5t   = (__bf16*)(ws + 36987392);          // 458,752 B -> total ~37.4 MB

    hipMemsetAsync(featp, 0, (size_t)16*FPC*sizeof(float), stream);
    conv_enc_kernel<<<128, 256, 0, stream>>>(inp, Wenc, benc, featp);
    prep_weights_kernel<<<768, 256, 0, stream>>>(W2, W3, W4, Wt);
    prep_w5_kernel<<<256, 448, 0, stream>>>(W5, W5t);
    u_mfma_kernel<<<512, 512, 0, stream>>>(featp, W5t, U);
    s_kernel<<<128, 256, 0, stream>>>(featp, b5, S);
    query_mfma_kernel<<<3125, 512, 0, stream>>>(coord, cell, W1, b1, Wt,
                                                b2, b3, b4, U, S, out);
}

// Round 12
// 523.419 us; speedup vs baseline: 2.7609x; 1.0072x over previous
//
#include <hip/hip_runtime.h>
#include <cstddef>
#include <cstdint>

// ---------------------------------------------------------------------------
// MetaSR fused pipeline, MFMA bf16-split everywhere.
//   R12 delta: MFMA issue order in layer64/mfma7 restructured into 3 sweeps
//   of 8 independent MFMAs (round-robin over all 8 accumulators) so no
//   accumulator is reused within ~8 instructions -> hides MFMA dep latency.
// ---------------------------------------------------------------------------

#define FPC (34*34*34)   // 39304
#define FPD (34*34)      // 1156

typedef __bf16 v8bf  __attribute__((ext_vector_type(8)));
typedef __bf16 v4bf  __attribute__((ext_vector_type(4)));
typedef float  f32x4 __attribute__((ext_vector_type(4)));

#define MFMA16(a,b,c) __builtin_amdgcn_mfma_f32_16x16x32_bf16((a),(b),(c),0,0,0)
#define W5T_LO 114688   // 256*448, lo-plane offset in W5t

// ---------------- K1: conv encoder ----------------
__global__ void conv_enc_kernel(const float* __restrict__ inp,
                                const float* __restrict__ Wenc,
                                const float* __restrict__ benc,
                                float* __restrict__ featp)
{
    __shared__ float wl[432];
    __shared__ float bl[16];
    int t = threadIdx.x;
    for (int k = t; k < 432; k += 256) wl[k] = Wenc[k];
    if (t < 16) bl[t] = benc[t];
    __syncthreads();

    int vid = blockIdx.x * 256 + t;
    int d = vid >> 10, h = (vid >> 5) & 31, w = vid & 31;

    float v[27];
    #pragma unroll
    for (int dz = 0; dz < 3; dz++)
      #pragma unroll
      for (int dy = 0; dy < 3; dy++)
        #pragma unroll
        for (int dx = 0; dx < 3; dx++) {
            int zz = d + dz - 1, yy = h + dy - 1, xx = w + dx - 1;
            bool ok = (zz >= 0 && zz < 32 && yy >= 0 && yy < 32 && xx >= 0 && xx < 32);
            v[dz*9 + dy*3 + dx] = ok ? inp[(zz << 10) + (yy << 5) + xx] : 0.0f;
        }

    #pragma unroll
    for (int oc = 0; oc < 16; oc++) {
        float a = bl[oc];
        #pragma unroll
        for (int n = 0; n < 27; n++) a = fmaf(v[n], wl[oc*27 + n], a);
        featp[oc*FPC + (d+1)*FPD + (h+1)*34 + (w+1)] = a;
    }
}

// ---------------- Kp: MLP weight transpose + bf16 split ----------------
__global__ void prep_weights_kernel(const float* __restrict__ W2,
                                    const float* __restrict__ W3,
                                    const float* __restrict__ W4,
                                    __bf16* __restrict__ Wt)
{
    int l = blockIdx.x >> 8;        // 0..2
    int m = blockIdx.x & 255;
    const float* W = (l == 0) ? W2 : (l == 1) ? W3 : W4;
    int k = threadIdx.x;
    float w = W[k*256 + m];         // W is [k][m]; Wt is [m][k]
    __bf16 hi = (__bf16)w;
    __bf16 lo = (__bf16)(w - (float)hi);
    __bf16* base = Wt + (size_t)l * 131072;
    base[m*256 + k]         = hi;
    base[65536 + m*256 + k] = lo;
}

// ---------------- Kp5: W5 split + pad to 448 ----------------
__global__ void prep_w5_kernel(const float* __restrict__ W5,
                               __bf16* __restrict__ W5t)
{
    int j = blockIdx.x;             // 0..255 output row
    int k = threadIdx.x;            // 0..447
    float w = (k < 432) ? W5[j*432 + k] : 0.0f;
    __bf16 hi = (__bf16)w;
    __bf16 lo = (__bf16)(w - (float)hi);
    W5t[j*448 + k]          = hi;
    W5t[W5T_LO + j*448 + k] = lo;
}

// ---------------- K2: U precompute via MFMA ----------------
__device__ __forceinline__
void mfma7(const __bf16* __restrict__ w0, const __bf16* __restrict__ w1,
           const __bf16* fu_hi, const __bf16* fu_lo,
           int lr, int lk, f32x4 acc[2][4])
{
    v8bf cA0 = *(const v8bf*)(w0 + 8*lk);
    v8bf cA1 = *(const v8bf*)(w0 + W5T_LO + 8*lk);
    v8bf cA2 = *(const v8bf*)(w1 + 8*lk);
    v8bf cA3 = *(const v8bf*)(w1 + W5T_LO + 8*lk);

    #pragma unroll
    for (int ks = 0; ks < 7; ks++) {
        v8bf nA0, nA1, nA2, nA3;
        if (ks < 6) {
            const int kbn = (ks+1)*32 + 8*lk;
            nA0 = *(const v8bf*)(w0 + kbn);
            nA1 = *(const v8bf*)(w0 + W5T_LO + kbn);
            nA2 = *(const v8bf*)(w1 + kbn);
            nA3 = *(const v8bf*)(w1 + W5T_LO + kbn);
        }
        const int kb = ks*32 + 8*lk;
        const int kx = kb ^ (lr << 3);
        v8bf Bh[4], Bl[4];
        #pragma unroll
        for (int nj = 0; nj < 4; nj++) {
            const int q = nj*16 + lr;
            Bh[nj] = *(const v8bf*)(fu_hi + q*256 + kx);
            Bl[nj] = *(const v8bf*)(fu_lo + q*256 + kx);
        }
        // sweep 1: Ah . Bh  (8 independent)
        #pragma unroll
        for (int nj = 0; nj < 4; nj++) acc[0][nj] = MFMA16(cA0, Bh[nj], acc[0][nj]);
        #pragma unroll
        for (int nj = 0; nj < 4; nj++) acc[1][nj] = MFMA16(cA2, Bh[nj], acc[1][nj]);
        // sweep 2: Ah . Bl
        #pragma unroll
        for (int nj = 0; nj < 4; nj++) acc[0][nj] = MFMA16(cA0, Bl[nj], acc[0][nj]);
        #pragma unroll
        for (int nj = 0; nj < 4; nj++) acc[1][nj] = MFMA16(cA2, Bl[nj], acc[1][nj]);
        // sweep 3: Al . Bh
        #pragma unroll
        for (int nj = 0; nj < 4; nj++) acc[0][nj] = MFMA16(cA1, Bh[nj], acc[0][nj]);
        #pragma unroll
        for (int nj = 0; nj < 4; nj++) acc[1][nj] = MFMA16(cA3, Bh[nj], acc[1][nj]);

        if (ks < 6) { cA0 = nA0; cA1 = nA1; cA2 = nA2; cA3 = nA3; }
    }
}

__global__ __launch_bounds__(512, 4)
void u_mfma_kernel(const float* __restrict__ featp,
                   const __bf16* __restrict__ W5t,
                   float* __restrict__ U)
{
    __shared__ __align__(16) char smem[65536];
    __bf16* fu_hi = (__bf16*)smem;            // [64][256] bf16, swizzled
    __bf16* fu_lo = (__bf16*)(smem + 32768);

    const int t   = threadIdx.x;
    const int bid = blockIdx.x;               // 512 blocks, 64 vox each
    const int d   = bid >> 4;
    const int h0  = (bid & 15) << 1;

    const int vox = t & 63;
    const int vh = vox >> 5, w = vox & 31;
    const int sbase = d*FPD + (h0 + vh)*34 + w;
    const int sw_st = (vox & 15) << 3;

    const int l  = t & 63;
    const int wv = t >> 6;
    const int m0 = wv << 5;
    const int lr = l & 15;
    const int lk = l >> 4;

    f32x4 acc[2][4];
    #pragma unroll
    for (int ms = 0; ms < 2; ms++)
      #pragma unroll
      for (int nj = 0; nj < 4; nj++)
        acc[ms][nj] = (f32x4){0.f, 0.f, 0.f, 0.f};

    for (int half = 0; half < 2; half++) {
        #pragma unroll
        for (int loop = 0; loop < 4; loop++) {
            const int k0 = ((t >> 6) + 8*loop) * 8;   // 0,8,...,248
            v8bf hv, lv;
            #pragma unroll
            for (int e = 0; e < 8; e++) {
                const int kg = half*224 + k0 + e;
                float v = 0.0f;
                if (k0 + e < 224 && kg < 432) {
                    const int c  = (kg*4855) >> 17;       // kg/27
                    const int n  = kg - c*27;
                    const int i  = (n*57) >> 9;           // n/9
                    const int m9 = n - 9*i;
                    const int j  = (m9*86) >> 8;          // m9/3
                    const int x  = m9 - 3*j;
                    v = featp[c*FPC + i*FPD + j*34 + x + sbase];
                }
                __bf16 hi = (__bf16)v;
                hv[e] = hi;
                lv[e] = (__bf16)(v - (float)hi);
            }
            const int idx = vox*256 + (k0 ^ sw_st);
            *(v8bf*)(fu_hi + idx) = hv;
            *(v8bf*)(fu_lo + idx) = lv;
        }
        __syncthreads();

        const __bf16* w0 = W5t + (m0 + lr)*448      + half*224;
        const __bf16* w1 = W5t + (m0 + 16 + lr)*448 + half*224;
        mfma7(w0, w1, fu_hi, fu_lo, lr, lk, acc);
        __syncthreads();
    }

    const size_t voxbase = (size_t)bid * 64;
    #pragma unroll
    for (int ms = 0; ms < 2; ms++)
      #pragma unroll
      for (int nj = 0; nj < 4; nj++) {
        const int q  = nj*16 + lr;
        const int mb = m0 + ms*16 + 4*lk;
        *(f32x4*)(U + (voxbase + q)*256 + mb) = acc[ms][nj];
      }
}

// ---------------- K2b: S[vox] = b5 . feat_u(:,vox) ----------------
__global__ void s_kernel(const float* __restrict__ featp,
                         const float* __restrict__ b5,
                         float* __restrict__ S)
{
    __shared__ float b5l[432];
    const int t = threadIdx.x;
    for (int k = t; k < 432; k += 256) b5l[k] = b5[k];
    __syncthreads();

    const int vox = blockIdx.x * 256 + t;
    const int d = vox >> 10, h = (vox >> 5) & 31, w = vox & 31;
    const int base = d*FPD + h*34 + w;

    float a0 = 0.f, a1 = 0.f, a2 = 0.f, a3 = 0.f;
    for (int c = 0; c < 16; c++) {
        const float* fp = featp + c*FPC + base;
        const float* bp = b5l + c*27;
        #pragma unroll
        for (int n = 0; n < 27; n++) {
            const int i = n/9, j = (n/3)%3, x = n%3;
            float v = fp[i*FPD + j*34 + x];
            if ((n & 3) == 0)      a0 = fmaf(bp[n], v, a0);
            else if ((n & 3) == 1) a1 = fmaf(bp[n], v, a1);
            else if ((n & 3) == 2) a2 = fmaf(bp[n], v, a2);
            else                   a3 = fmaf(bp[n], v, a3);
        }
    }
    S[vox] = ((a0 + a1) + (a2 + a3));
}

// ---------------- K3: fused query MLP (MFMA, 64 q/block) ----------------
template<int LAST>
__device__ __forceinline__
void layer64(const __bf16* __restrict__ Wly,   // hi plane; lo plane at +65536
             const float* __restrict__ bias,
             __bf16* act_hi, __bf16* act_lo, float* h4f, int t)
{
    const int l  = t & 63;
    const int wv = t >> 6;
    const int m0 = wv << 5;
    const int lr = l & 15;
    const int lk = l >> 4;

    f32x4 acc[2][4];
    {
        f32x4 bv0 = *(const f32x4*)(bias + m0 + 4*lk);
        f32x4 bv1 = *(const f32x4*)(bias + m0 + 16 + 4*lk);
        #pragma unroll
        for (int nj = 0; nj < 4; nj++) { acc[0][nj] = bv0; acc[1][nj] = bv1; }
    }

    const __bf16* w0 = Wly + (m0 + lr)*256;
    const __bf16* w1 = Wly + (m0 + 16 + lr)*256;

    v8bf cA0 = *(const v8bf*)(w0 + 8*lk);
    v8bf cA1 = *(const v8bf*)(w0 + 65536 + 8*lk);
    v8bf cA2 = *(const v8bf*)(w1 + 8*lk);
    v8bf cA3 = *(const v8bf*)(w1 + 65536 + 8*lk);

    #pragma unroll
    for (int k0 = 0; k0 < 8; k0++) {
        v8bf nA0, nA1, nA2, nA3;
        if (k0 < 7) {
            const int kbn = (k0+1)*32 + 8*lk;
            nA0 = *(const v8bf*)(w0 + kbn);
            nA1 = *(const v8bf*)(w0 + 65536 + kbn);
            nA2 = *(const v8bf*)(w1 + kbn);
            nA3 = *(const v8bf*)(w1 + 65536 + kbn);
        }
        const int kb = k0*32 + 8*lk;
        const int kx = kb ^ (lr << 3);
        v8bf Bh[4], Bl[4];
        #pragma unroll
        for (int nj = 0; nj < 4; nj++) {
            const int q = nj*16 + lr;
            Bh[nj] = *(const v8bf*)(act_hi + q*256 + kx);
            Bl[nj] = *(const v8bf*)(act_lo + q*256 + kx);
        }
        // sweep 1: Ah . Bh  (8 independent MFMAs)
        #pragma unroll
        for (int nj = 0; nj < 4; nj++) acc[0][nj] = MFMA16(cA0, Bh[nj], acc[0][nj]);
        #pragma unroll
        for (int nj = 0; nj < 4; nj++) acc[1][nj] = MFMA16(cA2, Bh[nj], acc[1][nj]);
        // sweep 2: Ah . Bl
        #pragma unroll
        for (int nj = 0; nj < 4; nj++) acc[0][nj] = MFMA16(cA0, Bl[nj], acc[0][nj]);
        #pragma unroll
        for (int nj = 0; nj < 4; nj++) acc[1][nj] = MFMA16(cA2, Bl[nj], acc[1][nj]);
        // sweep 3: Al . Bh
        #pragma unroll
        for (int nj = 0; nj < 4; nj++) acc[0][nj] = MFMA16(cA1, Bh[nj], acc[0][nj]);
        #pragma unroll
        for (int nj = 0; nj < 4; nj++) acc[1][nj] = MFMA16(cA3, Bh[nj], acc[1][nj]);

        if (k0 < 7) { cA0 = nA0; cA1 = nA1; cA2 = nA2; cA3 = nA3; }
    }

    __syncthreads();

    #pragma unroll
    for (int ms = 0; ms < 2; ms++)
      #pragma unroll
      for (int nj = 0; nj < 4; nj++) {
        const int q  = nj*16 + lr;
        const int mb = m0 + ms*16 + 4*lk;
        if (LAST) {
            f32x4 v;
            #pragma unroll
            for (int r = 0; r < 4; r++) v[r] = fmaxf(acc[ms][nj][r], 0.0f);
            *(f32x4*)(h4f + q*256 + (mb ^ ((q & 15) << 2))) = v;
        } else {
            v4bf hv, lv;
            #pragma unroll
            for (int r = 0; r < 4; r++) {
                float a = fmaxf(acc[ms][nj][r], 0.0f);
                __bf16 hi = (__bf16)a;
                hv[r] = hi;
                lv[r] = (__bf16)(a - (float)hi);
            }
            const int idx = q*256 + (mb ^ ((q & 15) << 3));
            *(v4bf*)(act_hi + idx) = hv;
            *(v4bf*)(act_lo + idx) = lv;
        }
      }
    __syncthreads();
}

__global__ __launch_bounds__(512, 4)
void query_mfma_kernel(const float* __restrict__ coord, const float* __restrict__ cell,
                       const float* __restrict__ W1, const float* __restrict__ b1,
                       const __bf16* __restrict__ Wt,
                       const float* __restrict__ b2, const float* __restrict__ b3,
                       const float* __restrict__ b4,
                       const float* __restrict__ U, const float* __restrict__ S,
                       float* __restrict__ out)
{
    __shared__ __align__(16) char smem[65536];
    __bf16* act_hi = (__bf16*)(smem);
    __bf16* act_lo = (__bf16*)(smem + 32768);
    float*  h4f    = (float*)(smem);
    float*  xS     = (float*)(smem);

    const int t = threadIdx.x;
    const int qbase = blockIdx.x * 64;

    if (t < 64) {
        int gq = qbase + t;
        float c0 = coord[3*gq+0], c1 = coord[3*gq+1], c2 = coord[3*gq+2];
        float e0 = cell[3*gq+0],  e1 = cell[3*gq+1],  e2 = cell[3*gq+2];
        float x0 = c0 - e0*0.5f, x1 = c1 - e1*0.5f, x2 = c2 - e2*0.5f;

        float f0 = rintf(((x0 + 1.0f)*32.0f - 1.0f)*0.5f);
        float f1 = rintf(((x1 + 1.0f)*32.0f - 1.0f)*0.5f);
        float f2 = rintf(((x2 + 1.0f)*32.0f - 1.0f)*0.5f);
        bool valid = (f0 >= 0.0f && f0 < 32.0f &&
                      f1 >= 0.0f && f1 < 32.0f &&
                      f2 >= 0.0f && f2 < 32.0f);
        int i0 = min(max((int)f0, 0), 31);
        int i1 = min(max((int)f1, 0), 31);
        int i2 = min(max((int)f2, 0), 31);
        float qc0 = -0.96875f + 0.0625f*(float)i0;
        float qc1 = -0.96875f + 0.0625f*(float)i1;
        float qc2 = -0.96875f + 0.0625f*(float)i2;
        float adj = (i2 == 0 || i2 == 1 || i2 == 3) ? -0.03125f : 0.0f;
        qc0 += adj; qc1 += adj; qc2 += adj;
        if (!valid) { qc0 = 0.0f; qc1 = 0.0f; qc2 = 0.0f; }

        xS[0*64 + t] = (x0 - qc0)*32.0f;
        xS[1*64 + t] = (x1 - qc1)*32.0f;
        xS[2*64 + t] = (x2 - qc2)*32.0f;
        xS[3*64 + t] = e0 * 16.0f;
    }
    __syncthreads();

    {
        const int q  = t & 63;
        const int jg = (t >> 6) * 32;
        float x0 = xS[q], x1 = xS[64+q], x2 = xS[128+q], x3 = xS[192+q];
        float vals[32];
        #pragma unroll
        for (int i = 0; i < 32; i++) {
            int j = jg + i;
            float a = b1[j];
            a = fmaf(x0, W1[j],       a);
            a = fmaf(x1, W1[256 + j], a);
            a = fmaf(x2, W1[512 + j], a);
            a = fmaf(x3, W1[768 + j], a);
            vals[i] = fmaxf(a, 0.0f);
        }
        __syncthreads();
        const int sw = (q & 15) << 3;
        #pragma unroll
        for (int g = 0; g < 4; g++) {
            v8bf hv, lv;
            #pragma unroll
            for (int e = 0; e < 8; e++) {
                float a = vals[g*8 + e];
                __bf16 hi = (__bf16)a;
                hv[e] = hi;
                lv[e] = (__bf16)(a - (float)hi);
            }
            const int idx = q*256 + ((jg + g*8) ^ sw);
            *(v8bf*)(act_hi + idx) = hv;
            *(v8bf*)(act_lo + idx) = lv;
        }
    }
    __syncthreads();

    layer64<0>(Wt,          b2, act_hi, act_lo, nullptr, t);
    layer64<0>(Wt + 131072, b3, act_hi, act_lo, nullptr, t);
    layer64<1>(Wt + 262144, b4, act_hi, act_lo, h4f, t);

    {
        const int q = t >> 3, part = t & 7;
        const int gq = qbase + q;
        float c0 = coord[3*gq+0], c1 = coord[3*gq+1], c2 = coord[3*gq+2];
        float e0 = cell[3*gq+0],  e1 = cell[3*gq+1],  e2 = cell[3*gq+2];
        const float LO = (float)(-1.0 + 1e-6);
        const float HI = (float)( 1.0 - 1e-6);
        float x0 = fminf(fmaxf(c0 - e0*0.5f + 1e-6f, LO), HI);
        float x1 = fminf(fmaxf(c1 - e1*0.5f + 1e-6f, LO), HI);
        float x2 = fminf(fmaxf(c2 - e2*0.5f + 1e-6f, LO), HI);
        int i0 = min(max((int)rintf(((x0 + 1.0f)*32.0f - 1.0f)*0.5f), 0), 31);
        int i1 = min(max((int)rintf(((x1 + 1.0f)*32.0f - 1.0f)*0.5f), 0), 31);
        int i2 = min(max((int)rintf(((x2 + 1.0f)*32.0f - 1.0f)*0.5f), 0), 31);
        int vox = (i0 << 10) + (i1 << 5) + i2;

        const float* Ur   = U + (size_t)vox*256 + part*32;
        const float* hrow = h4f + q*256;
        const int sw = (q & 15) << 2;
        float sum = 0.0f;
        #pragma unroll
        for (int i = 0; i < 32; i += 4) {
            float4 u = *(const float4*)(Ur + i);
            f32x4 h = *(const f32x4*)(hrow + ((part*32 + i) ^ sw));
            sum = fmaf(u.x, h[0], sum);
            sum = fmaf(u.y, h[1], sum);
            sum = fmaf(u.z, h[2], sum);
            sum = fmaf(u.w, h[3], sum);
        }
        sum += __shfl_down(sum, 4);
        sum += __shfl_down(sum, 2);
        sum += __shfl_down(sum, 1);
        if (part == 0) out[gq] = sum + S[vox];
    }
}

// ---------------------------------------------------------------------------
extern "C" void kernel_launch(void* const* d_in, const int* in_sizes, int n_in,
                              void* d_out, int out_size, void* d_ws, size_t ws_size,
                              hipStream_t stream)
{
    const float* inp   = (const float*)d_in[0];
    const float* coord = (const float*)d_in[1];
    const float* cell  = (const float*)d_in[2];
    const float* Wenc  = (const float*)d_in[3];
    const float* benc  = (const float*)d_in[4];
    const float* W1 = (const float*)d_in[5];  const float* b1 = (const float*)d_in[6];
    const float* W2 = (const float*)d_in[7];  const float* b2 = (const float*)d_in[8];
    const float* W3 = (const float*)d_in[9];  const float* b3 = (const float*)d_in[10];
    const float* W4 = (const float*)d_in[11]; const float* b4 = (const float*)d_in[12];
    const float* W5 = (const float*)d_in[13]; const float* b5 = (const float*)d_in[14];
    float* out = (float*)d_out;

    char* ws = (char*)d_ws;
    float*  featp = (float*)ws;                        // 2,515,456 B
    float*  U     = (float*)(ws + 2515456);            // 33,554,432 B
    float*  S     = (float*)(ws + 36069888);           // 131,072 B
    __bf16* Wt    = (__bf16*)(ws + 36200960);          // 786,432 B (MLP)
    __bf16* W5t   = (__bf16*)(ws + 36987392);          // 458,752 B -> total ~37.4 MB

    hipMemsetAsync(featp, 0, (size_t)16*FPC*sizeof(float), stream);
    conv_enc_kernel<<<128, 256, 0, stream>>>(inp, Wenc, benc, featp);
    prep_weights_kernel<<<768, 256, 0, stream>>>(W2, W3, W4, Wt);
    prep_w5_kernel<<<256, 448, 0, stream>>>(W5, W5t);
    u_mfma_kernel<<<512, 512, 0, stream>>>(featp, W5t, U);
    s_kernel<<<128, 256, 0, stream>>>(featp, b5, S);
    query_mfma_kernel<<<3125, 512, 0, stream>>>(coord, cell, W1, b1, Wt,
                                                b2, b3, b4, U, S, out);
}